// Round 4
// baseline (546.041 us; speedup 1.0000x reference)
//
#include <hip/hip_runtime.h>
#include <hip/hip_bf16.h>
#include <cstdint>
#include <cstddef>

#define NNODES 20000
#define MNB    16
#define NFEAT  500
#define OUTC   656

typedef short short8 __attribute__((ext_vector_type(8)));
typedef float floatx4 __attribute__((ext_vector_type(4)));
typedef float v2f __attribute__((ext_vector_type(2)));

__device__ __forceinline__ float bf2f(unsigned int h) {
    union { unsigned int u; float f; } v; v.u = h << 16; return v.f;
}
__device__ __forceinline__ unsigned short f2bf(float f) {
    union { float f; unsigned int u; } v; v.f = f;
    unsigned int u = v.u;
    u += 0x7FFFu + ((u >> 16) & 1u);   // RNE
    return (unsigned short)(u >> 16);
}

// packed fp32 math (2x rate on CDNA): explicit VOP3P via asm.
__device__ __forceinline__ v2f pk_mul(v2f a, v2f b) {
    v2f d;
    asm("v_pk_mul_f32 %0, %1, %2 op_sel:[0,0] op_sel_hi:[1,1]"
        : "=v"(d) : "v"(a), "v"(b));
    return d;
}
__device__ __forceinline__ v2f pk_fma(v2f a, v2f b, v2f c) {
    v2f d;
    asm("v_pk_fma_f32 %0, %1, %2, %3 op_sel:[0,0,0] op_sel_hi:[1,1,1]"
        : "=v"(d) : "v"(a), "v"(b), "v"(c));
    return d;
}

// Opaque register pin: forces the value to be carried in a VGPR (the asm
// output is not rematerializable from memory).
#define PIN(x) asm volatile("" : "+v"(x))

// 16-lane (DPP-row) replicated sum, one stage. Call sites are stage-major
// across many independent components so the VALU->DPP hazard slots are
// filled by neighboring components.
template<int CTRL>
__device__ __forceinline__ float dpp_add(float v) {
    const int o = __builtin_amdgcn_update_dpp(0, __float_as_int(v), CTRL, 0xF, 0xF, true);
    return v + __int_as_float(o);
}
__device__ __forceinline__ float sum16(float v) {
    v = dpp_add<0xB1>(v);    // quad_perm xor1
    v = dpp_add<0x4E>(v);    // quad_perm xor2
    v = dpp_add<0x141>(v);   // row_half_mirror
    v = dpp_add<0x140>(v);   // row_mirror
    return v;
}

// ---------------- dtype probe
__global__ __launch_bounds__(64) void detect_kernel(const unsigned short* __restrict__ fx,
                                                    int* __restrict__ flag) {
    const int tid = threadIdx.x;
    const unsigned short s = fx[2 * tid];
    const int e = (s >> 7) & 0xFF;
    const bool ok = (e >= 100 && e <= 140);
    const unsigned long long m = __ballot(ok);
    if (tid == 0) *flag = (__popcll(m) >= 32) ? 1 : 0;
}

// ---------------- convert all weights/biases to one fp32 blob in ws
struct WPtrs { const void* p[12]; };

__global__ __launch_bounds__(256) void convert_weights(WPtrs ptrs, const int* __restrict__ flag,
                                                       float* __restrict__ outb) {
    constexpr int SN[12] = {64000,128,14336,112,10752,96,7680,80,5120,64,3072,48};
    constexpr int SO[12] = {0,64000,64128,78464,78576,89328,89424,97104,97184,102304,102368,105440};
    constexpr int TOT = 105488;
    const int i = blockIdx.x * 256 + threadIdx.x;
    if (i >= TOT) return;
    const bool isbf = (*flag != 0);
    int seg = 0, local = i;
#pragma unroll
    for (int s = 0; s < 12; ++s) {
        if (i >= SO[s] && i < SO[s] + SN[s]) { seg = s; local = i - SO[s]; }
    }
    const void* src = ptrs.p[seg];
    float v;
    if (isbf) v = bf2f(((const unsigned short*)src)[local]);
    else      v = ((const float*)src)[local];
    outb[i] = v;
}

// ---------------- pad pca_w (fp32 blob) -> bf16 [128][512] (K-padded with zeros)
__global__ __launch_bounds__(256) void convert_wpad(const float* __restrict__ wblob,
                                                    unsigned short* __restrict__ wpad) {
    const int i = blockIdx.x * 256 + threadIdx.x;   // 128*512 = 65536
    const int n = i >> 9, k = i & 511;
    const float v = (k < NFEAT) ? wblob[n * NFEAT + k] : 0.f;
    wpad[i] = f2bf(v);
}

// ---------------- PCA via MFMA (fp32 OR bf16 feature; inline bf16 conversion)
__global__ __launch_bounds__(256) void pca_mfma(
    const void* __restrict__ feat_raw,
    const unsigned short* __restrict__ wpad,   // [128][512] bf16
    const float* __restrict__ bias,
    const int* __restrict__ flag,
    float* __restrict__ xn,
    void* __restrict__ out_raw)
{
    __shared__ short sA[32 * 56];   // stride 56 shorts (112 B): 2-way banks = free
    __shared__ short sB[128 * 56];
    const int tid = threadIdx.x;
    const int l = tid & 63, wv = tid >> 6;
    const int m = l & 15, q = l >> 4;
    const int rt = wv >> 1, ch = wv & 1;       // row-tile, col-half
    const int r0 = blockIdx.x * 32;
    const bool isbf = (*flag != 0);

    const int arow = tid >> 3, aseg = tid & 7;

    floatx4 acc[4];
#pragma unroll
    for (int t = 0; t < 4; ++t) acc[t] = 0;

    for (int c = 0; c < 16; ++c) {
        const int k0 = c * 32;
        __syncthreads();
        {
            const int k = k0 + aseg * 4;
            uint2 v = make_uint2(0u, 0u);
            if (k < NFEAT) {
                if (isbf) {
                    v = *(const uint2*)((const unsigned short*)feat_raw +
                                        (size_t)(r0 + arow) * NFEAT + k);
                } else {
                    const float4 f = *(const float4*)((const float*)feat_raw +
                                                      (size_t)(r0 + arow) * NFEAT + k);
                    v.x = ((unsigned int)f2bf(f.y) << 16) | f2bf(f.x);
                    v.y = ((unsigned int)f2bf(f.w) << 16) | f2bf(f.z);
                }
            }
            *(uint2*)&sA[arow * 56 + aseg * 4] = v;
        }
#pragma unroll
        for (int it = 0; it < 4; ++it) {
            const int idx = tid + 256 * it;
            const int row = idx >> 3, seg = idx & 7;
            const uint2 v = *(const uint2*)(wpad + (size_t)row * 512 + k0 + seg * 4);
            *(uint2*)&sB[row * 56 + seg * 4] = v;
        }
        __syncthreads();
        const short8 af = *(const short8*)&sA[(rt * 16 + m) * 56 + q * 8];
#pragma unroll
        for (int t = 0; t < 4; ++t) {
            const short8 bf = *(const short8*)&sB[((ch * 4 + t) * 16 + m) * 56 + q * 8];
            acc[t] = __builtin_amdgcn_mfma_f32_16x16x32_bf16(af, bf, acc[t], 0, 0, 0);
        }
    }

#pragma unroll
    for (int t = 0; t < 4; ++t) {
        const int col = (ch * 4 + t) * 16 + m;
        const float bb = bias[col];
#pragma unroll
        for (int r = 0; r < 4; ++r) {
            const int grow = r0 + rt * 16 + q * 4 + r;
            const float y = fmaxf(acc[t][r] + bb, 0.f);
            if (isbf) ((unsigned short*)out_raw)[(size_t)grow * OUTC + col] = f2bf(y);
            else      ((float*)out_raw)[(size_t)grow * OUTC + col] = y;
            const float ss = sum16(y * y);
            const float invn = 1.0f / fmaxf(sqrtf(ss), 1e-12f);
            xn[(size_t)grow * 128 + col] = y * invn;
        }
    }
}

// ---------------- linear via MFMA, bf16x3 split precision (~fp32 accuracy).
template<int FIN, int FOUT>
__global__ __launch_bounds__(256) void linear_mfma(
    const float* __restrict__ xin,
    const float* __restrict__ w,
    const float* __restrict__ bias,
    float* __restrict__ xn)
{
    constexpr int KP   = ((FIN + 31) / 32) * 32;
    constexpr int NCH  = KP / 32;
    constexpr int NTIL = 2 * (FOUT / 16);
    constexpr int MT   = (NTIL + 3) / 4;
    __shared__ short sAh[32 * 56], sAl[32 * 56];
    __shared__ short sBh[FOUT * 56], sBl[FOUT * 56];
    const int tid = threadIdx.x;
    const int l = tid & 63, wv = tid >> 6;
    const int m = l & 15, q = l >> 4;
    const int n0 = blockIdx.x * 32;

    floatx4 acc[MT];
#pragma unroll
    for (int i = 0; i < MT; ++i) acc[i] = 0;

    for (int c = 0; c < NCH; ++c) {
        const int k0 = c * 32;
        __syncthreads();
        {
            const int row = tid >> 3, seg = tid & 7;
            const int k = k0 + seg * 4;
            uint2 vh = make_uint2(0u, 0u), vl = make_uint2(0u, 0u);
            if (k < FIN) {
                const float4 f = *(const float4*)(xin + (size_t)(n0 + row) * FIN + k);
                const unsigned short h0 = f2bf(f.x), h1 = f2bf(f.y);
                const unsigned short h2 = f2bf(f.z), h3 = f2bf(f.w);
                const unsigned short e0 = f2bf(f.x - bf2f(h0)), e1 = f2bf(f.y - bf2f(h1));
                const unsigned short e2 = f2bf(f.z - bf2f(h2)), e3 = f2bf(f.w - bf2f(h3));
                vh = make_uint2(((unsigned)h1 << 16) | h0, ((unsigned)h3 << 16) | h2);
                vl = make_uint2(((unsigned)e1 << 16) | e0, ((unsigned)e3 << 16) | e2);
            }
            *(uint2*)&sAh[row * 56 + seg * 4] = vh;
            *(uint2*)&sAl[row * 56 + seg * 4] = vl;
        }
        for (int idx = tid; idx < FOUT * 8; idx += 256) {
            const int row = idx >> 3, seg = idx & 7;
            const int k = k0 + seg * 4;
            uint2 vh = make_uint2(0u, 0u), vl = make_uint2(0u, 0u);
            if (k < FIN) {
                const float4 f = *(const float4*)(w + (size_t)row * FIN + k);
                const unsigned short h0 = f2bf(f.x), h1 = f2bf(f.y);
                const unsigned short h2 = f2bf(f.z), h3 = f2bf(f.w);
                const unsigned short e0 = f2bf(f.x - bf2f(h0)), e1 = f2bf(f.y - bf2f(h1));
                const unsigned short e2 = f2bf(f.z - bf2f(h2)), e3 = f2bf(f.w - bf2f(h3));
                vh = make_uint2(((unsigned)h1 << 16) | h0, ((unsigned)h3 << 16) | h2);
                vl = make_uint2(((unsigned)e1 << 16) | e0, ((unsigned)e3 << 16) | e2);
            }
            *(uint2*)&sBh[row * 56 + seg * 4] = vh;
            *(uint2*)&sBl[row * 56 + seg * 4] = vl;
        }
        __syncthreads();
#pragma unroll
        for (int ti = 0; ti < MT; ++ti) {
            const int t = wv + ti * 4;
            if (t < NTIL) {
                const int rt = t & 1, ct = t >> 1;
                const int ao = (rt * 16 + m) * 56 + q * 8;
                const int bo = (ct * 16 + m) * 56 + q * 8;
                const short8 ah = *(const short8*)&sAh[ao];
                const short8 al = *(const short8*)&sAl[ao];
                const short8 bh = *(const short8*)&sBh[bo];
                const short8 bl = *(const short8*)&sBl[bo];
                floatx4 a = acc[ti];
                a = __builtin_amdgcn_mfma_f32_16x16x32_bf16(ah, bh, a, 0, 0, 0);
                a = __builtin_amdgcn_mfma_f32_16x16x32_bf16(ah, bl, a, 0, 0, 0);
                a = __builtin_amdgcn_mfma_f32_16x16x32_bf16(al, bh, a, 0, 0, 0);
                acc[ti] = a;
            }
        }
    }
#pragma unroll
    for (int ti = 0; ti < MT; ++ti) {
        const int t = wv + ti * 4;
        if (t < NTIL) {
            const int rt = t & 1, ct = t >> 1;
            const int col = ct * 16 + m;
            const float bb = bias[col];
#pragma unroll
            for (int r = 0; r < 4; ++r) {
                const int grow = n0 + rt * 16 + q * 4 + r;
                const float y = acc[ti][r] + bb;
                const float ss = sum16(y * y);
                const float invn = __builtin_amdgcn_rsqf(fmaxf(ss, 1e-24f));
                xn[(size_t)grow * FOUT + col] = y * invn;
            }
        }
    }
}

// ---------------- routing v7a: single-wave-per-node (K<=4). State = 48 floats.
// amdgpu_waves_per_eu(4,4) pins the VGPR budget to 128 (no occupancy-greedy
// remat); PIN() makes the loaded state non-rematerializable.
template<int K>
__global__ __launch_bounds__(256) __attribute__((amdgpu_waves_per_eu(4, 4)))
void routing3(
    const float* __restrict__ xn,
    const int* __restrict__ nb,
    float* __restrict__ xout,
    void* __restrict__ out_raw,
    const int* __restrict__ flag,
    const int coloff)
{
    constexpr int KD16 = K * 16;
    const int l = threadIdx.x & 63;
    const int wv = threadIdx.x >> 6;
    const int node = blockIdx.x * 4 + wv;
    const int j = l & 15, ks = l >> 4;
    const bool isbf = (*flag != 0);
    const int nid = nb[(size_t)node * 16 + j];
    const bool valid = (ks < K);

    v2f z[8], u[8], xv[8];
    {
        const float* zsrc = xn + (size_t)nid  * KD16 + ks * 16;
        const float* xsrc = xn + (size_t)node * KD16 + ks * 16;
#pragma unroll
        for (int q = 0; q < 4; ++q) {
            float4 zq = make_float4(0.f, 0.f, 0.f, 0.f);
            float4 xq = make_float4(0.f, 0.f, 0.f, 0.f);
            if (valid) {
                zq = *(const float4*)(zsrc + q * 4);
                xq = *(const float4*)(xsrc + q * 4);
            }
            v2f t0 = {zq.x, zq.y}; v2f t1 = {zq.z, zq.w};
            v2f t2 = {xq.x, xq.y}; v2f t3 = {xq.z, xq.w};
            z[2 * q] = t0; z[2 * q + 1] = t1;
            u[2 * q] = t2; u[2 * q + 1] = t3;
        }
        const v2f s16 = {0.0625f, 0.0625f};
#pragma unroll
        for (int h = 0; h < 8; ++h) xv[h] = pk_mul(u[h], s16);
    }
#pragma unroll
    for (int h = 0; h < 8; ++h) { PIN(z[h]); PIN(u[h]); PIN(xv[h]); }
    float invn = 1.0f;

    for (int t = 0; t < 5; ++t) {
        v2f da0 = pk_mul(z[0], u[0]);
        v2f da1 = pk_mul(z[1], u[1]);
#pragma unroll
        for (int h = 2; h < 8; h += 2) {
            da0 = pk_fma(z[h],     u[h],     da0);
            da1 = pk_fma(z[h + 1], u[h + 1], da1);
        }
        const float p = valid ? (da0[0] + da0[1] + da1[0] + da1[1]) * invn : -1e4f;
        const float e = __expf(p);
        float s = e;
        s += __shfl_xor(s, 16);
        s += __shfl_xor(s, 32);
        const float es = e * __builtin_amdgcn_rcpf(s);
        const v2f ev = {es, es};
#pragma unroll
        for (int h = 0; h < 8; ++h) u[h] = pk_fma(ev, z[h], xv[h]);
        // stage-major butterfly over 16 neighbor lanes
#pragma unroll
        for (int h = 0; h < 8; ++h) { u[h][0] = dpp_add<0xB1>(u[h][0]);  u[h][1] = dpp_add<0xB1>(u[h][1]); }
#pragma unroll
        for (int h = 0; h < 8; ++h) { u[h][0] = dpp_add<0x4E>(u[h][0]);  u[h][1] = dpp_add<0x4E>(u[h][1]); }
#pragma unroll
        for (int h = 0; h < 8; ++h) { u[h][0] = dpp_add<0x141>(u[h][0]); u[h][1] = dpp_add<0x141>(u[h][1]); }
#pragma unroll
        for (int h = 0; h < 8; ++h) { u[h][0] = dpp_add<0x140>(u[h][0]); u[h][1] = dpp_add<0x140>(u[h][1]); }
        if (t < 4) {
            v2f na0 = pk_mul(u[0], u[0]);
            v2f na1 = pk_mul(u[1], u[1]);
#pragma unroll
            for (int h = 2; h < 8; h += 2) {
                na0 = pk_fma(u[h],     u[h],     na0);
                na1 = pk_fma(u[h + 1], u[h + 1], na1);
            }
            invn = __builtin_amdgcn_rsqf(fmaxf(na0[0] + na0[1] + na1[0] + na1[1], 1e-24f));
        }
    }

#pragma unroll
    for (int h = 0; h < 8; ++h) {
        u[h][0] = fmaxf(u[h][0], 0.f);
        u[h][1] = fmaxf(u[h][1], 0.f);
    }
    if (valid && j < 4) {
        v2f a = u[0], b = u[1];
        if (j == 1)      { a = u[2]; b = u[3]; }
        else if (j == 2) { a = u[4]; b = u[5]; }
        else if (j == 3) { a = u[6]; b = u[7]; }
        const float4 w4 = make_float4(a[0], a[1], b[0], b[1]);
        *(float4*)(xout + (size_t)node * KD16 + ks * 16 + j * 4) = w4;
        const size_t ooff = (size_t)node * OUTC + coloff + ks * 16 + j * 4;
        if (isbf) {
            uint2 pk;
            pk.x = ((unsigned int)f2bf(w4.y) << 16) | f2bf(w4.x);
            pk.y = ((unsigned int)f2bf(w4.w) << 16) | f2bf(w4.z);
            *(uint2*)((unsigned short*)out_raw + ooff) = pk;
        } else {
            *(float4*)((float*)out_raw + ooff) = w4;
        }
    }
}

// ---------------- routing v7b: TWO waves per node (K in 5..8), state = 48
// floats/lane, pinned in registers; cross-wave softmax denominator via 512-B
// LDS exchange (parity double-buffered, one barrier per iteration).
template<int K>
__global__ __launch_bounds__(256) __attribute__((amdgpu_waves_per_eu(4, 4)))
void routing_dual(
    const float* __restrict__ xn,
    const int* __restrict__ nb,
    float* __restrict__ xout,
    void* __restrict__ out_raw,
    const int* __restrict__ flag,
    const int coloff)
{
    constexpr int KD16 = K * 16;
    __shared__ float sden[2][2][2][16];   // [parity][node-in-block][half][j]
    const int tid = threadIdx.x;
    const int l = tid & 63, wv = tid >> 6;
    const int nib = wv >> 1, half = wv & 1;
    const int node = blockIdx.x * 2 + nib;
    const int j = l & 15, kq = l >> 4;
    const int k = half * 4 + kq;           // capsule owned by this lane
    const bool valid = (k < K);
    const bool isbf = (*flag != 0);
    const int nid = nb[(size_t)node * 16 + j];

    v2f z[8], u[8], xv[8];
    {
        const float* zsrc = xn + (size_t)nid  * KD16 + k * 16;
        const float* xsrc = xn + (size_t)node * KD16 + k * 16;
#pragma unroll
        for (int q = 0; q < 4; ++q) {
            float4 zq = make_float4(0.f, 0.f, 0.f, 0.f);
            float4 xq = make_float4(0.f, 0.f, 0.f, 0.f);
            if (valid) {
                zq = *(const float4*)(zsrc + q * 4);
                xq = *(const float4*)(xsrc + q * 4);
            }
            v2f t0 = {zq.x, zq.y}; v2f t1 = {zq.z, zq.w};
            v2f t2 = {xq.x, xq.y}; v2f t3 = {xq.z, xq.w};
            z[2 * q] = t0; z[2 * q + 1] = t1;
            u[2 * q] = t2; u[2 * q + 1] = t3;
        }
        const v2f s16 = {0.0625f, 0.0625f};
#pragma unroll
        for (int h = 0; h < 8; ++h) xv[h] = pk_mul(u[h], s16);
    }
#pragma unroll
    for (int h = 0; h < 8; ++h) { PIN(z[h]); PIN(u[h]); PIN(xv[h]); }
    float invn = 1.0f;

    for (int t = 0; t < 5; ++t) {
        // agreement score for this lane's capsule (two interleaved fma chains)
        v2f da0 = pk_mul(z[0], u[0]);
        v2f da1 = pk_mul(z[1], u[1]);
#pragma unroll
        for (int h = 2; h < 8; h += 2) {
            da0 = pk_fma(z[h],     u[h],     da0);
            da1 = pk_fma(z[h + 1], u[h + 1], da1);
        }
        const float p = valid ? (da0[0] + da0[1] + da1[0] + da1[1]) * invn : -1e4f;
        const float e = __expf(p);
        // partial softmax denominator over this wave's 4 capsules
        float s = e;
        s += __shfl_xor(s, 16);
        s += __shfl_xor(s, 32);
        // cross-wave: exchange half-partials through LDS (parity double-buffer)
        if (l < 16) sden[t & 1][nib][half][j] = s;
        __syncthreads();
        s += sden[t & 1][nib][half ^ 1][j];
        const float es = e * __builtin_amdgcn_rcpf(s);
        const v2f ev = {es, es};
#pragma unroll
        for (int h = 0; h < 8; ++h) u[h] = pk_fma(ev, z[h], xv[h]);
        // stage-major butterfly over 16 neighbor lanes
#pragma unroll
        for (int h = 0; h < 8; ++h) { u[h][0] = dpp_add<0xB1>(u[h][0]);  u[h][1] = dpp_add<0xB1>(u[h][1]); }
#pragma unroll
        for (int h = 0; h < 8; ++h) { u[h][0] = dpp_add<0x4E>(u[h][0]);  u[h][1] = dpp_add<0x4E>(u[h][1]); }
#pragma unroll
        for (int h = 0; h < 8; ++h) { u[h][0] = dpp_add<0x141>(u[h][0]); u[h][1] = dpp_add<0x141>(u[h][1]); }
#pragma unroll
        for (int h = 0; h < 8; ++h) { u[h][0] = dpp_add<0x140>(u[h][0]); u[h][1] = dpp_add<0x140>(u[h][1]); }
        // capsule norm for next iteration (per-lane, no cross-lane needed)
        if (t < 4) {
            v2f na0 = pk_mul(u[0], u[0]);
            v2f na1 = pk_mul(u[1], u[1]);
#pragma unroll
            for (int h = 2; h < 8; h += 2) {
                na0 = pk_fma(u[h],     u[h],     na0);
                na1 = pk_fma(u[h + 1], u[h + 1], na1);
            }
            invn = __builtin_amdgcn_rsqf(fmaxf(na0[0] + na0[1] + na1[0] + na1[1], 1e-24f));
        }
    }

    // relu + store (u replicated across j-lanes; lanes j<4 write 4 dims each)
#pragma unroll
    for (int h = 0; h < 8; ++h) {
        u[h][0] = fmaxf(u[h][0], 0.f);
        u[h][1] = fmaxf(u[h][1], 0.f);
    }
    if (valid && j < 4) {
        v2f a = u[0], b = u[1];
        if (j == 1)      { a = u[2]; b = u[3]; }
        else if (j == 2) { a = u[4]; b = u[5]; }
        else if (j == 3) { a = u[6]; b = u[7]; }
        const float4 w4 = make_float4(a[0], a[1], b[0], b[1]);
        *(float4*)(xout + (size_t)node * KD16 + k * 16 + j * 4) = w4;
        const size_t ooff = (size_t)node * OUTC + coloff + k * 16 + j * 4;
        if (isbf) {
            uint2 pk;
            pk.x = ((unsigned int)f2bf(w4.y) << 16) | f2bf(w4.x);
            pk.y = ((unsigned int)f2bf(w4.w) << 16) | f2bf(w4.z);
            *(uint2*)((unsigned short*)out_raw + ooff) = pk;
        } else {
            *(float4*)((float*)out_raw + ooff) = w4;
        }
    }
}

extern "C" void kernel_launch(void* const* d_in, const int* in_sizes, int n_in,
                              void* d_out, int out_size, void* d_ws, size_t ws_size,
                              hipStream_t stream) {
    const int* nbid = (const int*)d_in[1];

    int*            flag  = (int*)d_ws;
    float*          wblob = (float*)((char*)d_ws + 16);
    unsigned short* wpad  = (unsigned short*)((char*)d_ws + (448 << 10));
    float*          xn    = (float*)((char*)d_ws + (1 << 20));
    float*          xc    = xn + (size_t)NNODES * 128;

    float* pw = wblob +      0; float* pb = wblob +  64000;
    float* w1 = wblob +  64128; float* b1 = wblob +  78464;
    float* w2 = wblob +  78576; float* b2 = wblob +  89328;
    float* w3 = wblob +  89424; float* b3 = wblob +  97104;
    float* w4 = wblob +  97184; float* b4 = wblob + 102304;
    float* w5 = wblob + 102368; float* b5 = wblob + 105440;

    hipLaunchKernelGGL(detect_kernel, dim3(1), dim3(64), 0, stream,
                       (const unsigned short*)d_in[0], flag);

    WPtrs wp;
    for (int i = 0; i < 12; ++i) wp.p[i] = d_in[i + 2];
    hipLaunchKernelGGL(convert_weights, dim3(413), dim3(256), 0, stream, wp, flag, wblob);
    hipLaunchKernelGGL(convert_wpad, dim3(256), dim3(256), 0, stream, pw, wpad);

    hipLaunchKernelGGL(pca_mfma, dim3(NNODES / 32), dim3(256), 0, stream,
                       d_in[0], wpad, pb, flag, xn, d_out);

    const int dgrid = NNODES / 2;   // routing_dual: 2 nodes/block
    const int rgrid = NNODES / 4;   // routing3: 4 nodes/block
    const int lgrid = NNODES / 32;

    hipLaunchKernelGGL((routing_dual<8>), dim3(dgrid), dim3(256), 0, stream,
                       xn, nbid, xc, d_out, flag, 128);
    hipLaunchKernelGGL((linear_mfma<128, 112>), dim3(lgrid), dim3(256), 0, stream,
                       xc, w1, b1, xn);

    hipLaunchKernelGGL((routing_dual<7>), dim3(dgrid), dim3(256), 0, stream,
                       xn, nbid, xc, d_out, flag, 256);
    hipLaunchKernelGGL((linear_mfma<112, 96>), dim3(lgrid), dim3(256), 0, stream,
                       xc, w2, b2, xn);

    hipLaunchKernelGGL((routing_dual<6>), dim3(dgrid), dim3(256), 0, stream,
                       xn, nbid, xc, d_out, flag, 368);
    hipLaunchKernelGGL((linear_mfma<96, 80>), dim3(lgrid), dim3(256), 0, stream,
                       xc, w3, b3, xn);

    hipLaunchKernelGGL((routing_dual<5>), dim3(dgrid), dim3(256), 0, stream,
                       xn, nbid, xc, d_out, flag, 464);
    hipLaunchKernelGGL((linear_mfma<80, 64>), dim3(lgrid), dim3(256), 0, stream,
                       xc, w4, b4, xn);

    hipLaunchKernelGGL((routing3<4>), dim3(rgrid), dim3(256), 0, stream,
                       xn, nbid, xc, d_out, flag, 544);
    hipLaunchKernelGGL((linear_mfma<64, 48>), dim3(lgrid), dim3(256), 0, stream,
                       xc, w5, b5, xn);

    hipLaunchKernelGGL((routing3<3>), dim3(rgrid), dim3(256), 0, stream,
                       xn, nbid, xc, d_out, flag, 608);
}

// Round 5
// 500.679 us; speedup vs baseline: 1.0906x; 1.0906x over previous
//
#include <hip/hip_runtime.h>
#include <hip/hip_bf16.h>
#include <cstdint>
#include <cstddef>

#define NNODES 20000
#define MNB    16
#define NFEAT  500
#define OUTC   656

typedef short short8 __attribute__((ext_vector_type(8)));
typedef float floatx4 __attribute__((ext_vector_type(4)));
typedef float v2f __attribute__((ext_vector_type(2)));

__device__ __forceinline__ float bf2f(unsigned int h) {
    union { unsigned int u; float f; } v; v.u = h << 16; return v.f;
}
__device__ __forceinline__ unsigned short f2bf(float f) {
    union { float f; unsigned int u; } v; v.f = f;
    unsigned int u = v.u;
    u += 0x7FFFu + ((u >> 16) & 1u);   // RNE
    return (unsigned short)(u >> 16);
}

// packed fp32 math (2x rate on CDNA): explicit VOP3P via asm.
__device__ __forceinline__ v2f pk_mul(v2f a, v2f b) {
    v2f d;
    asm("v_pk_mul_f32 %0, %1, %2 op_sel:[0,0] op_sel_hi:[1,1]"
        : "=v"(d) : "v"(a), "v"(b));
    return d;
}
__device__ __forceinline__ v2f pk_fma(v2f a, v2f b, v2f c) {
    v2f d;
    asm("v_pk_fma_f32 %0, %1, %2, %3 op_sel:[0,0,0] op_sel_hi:[1,1,1]"
        : "=v"(d) : "v"(a), "v"(b), "v"(c));
    return d;
}
__device__ __forceinline__ v2f pk_add(v2f a, v2f b) {
    v2f d;
    asm("v_pk_add_f32 %0, %1, %2 op_sel:[0,0] op_sel_hi:[1,1]"
        : "=v"(d) : "v"(a), "v"(b));
    return d;
}

// 16-lane (DPP-row) replicated sum, one stage. Call sites are stage-major
// across many independent components so the VALU->DPP hazard slots are
// filled by neighboring components.
template<int CTRL>
__device__ __forceinline__ float dpp_add(float v) {
    const int o = __builtin_amdgcn_update_dpp(0, __float_as_int(v), CTRL, 0xF, 0xF, true);
    return v + __int_as_float(o);
}
__device__ __forceinline__ float sum16(float v) {
    v = dpp_add<0xB1>(v);    // quad_perm xor1
    v = dpp_add<0x4E>(v);    // quad_perm xor2
    v = dpp_add<0x141>(v);   // row_half_mirror
    v = dpp_add<0x140>(v);   // row_mirror
    return v;
}

// ---------------- dtype probe
__global__ __launch_bounds__(64) void detect_kernel(const unsigned short* __restrict__ fx,
                                                    int* __restrict__ flag) {
    const int tid = threadIdx.x;
    const unsigned short s = fx[2 * tid];
    const int e = (s >> 7) & 0xFF;
    const bool ok = (e >= 100 && e <= 140);
    const unsigned long long m = __ballot(ok);
    if (tid == 0) *flag = (__popcll(m) >= 32) ? 1 : 0;
}

// ---------------- convert all weights/biases to one fp32 blob in ws
struct WPtrs { const void* p[12]; };

__global__ __launch_bounds__(256) void convert_weights(WPtrs ptrs, const int* __restrict__ flag,
                                                       float* __restrict__ outb) {
    constexpr int SN[12] = {64000,128,14336,112,10752,96,7680,80,5120,64,3072,48};
    constexpr int SO[12] = {0,64000,64128,78464,78576,89328,89424,97104,97184,102304,102368,105440};
    constexpr int TOT = 105488;
    const int i = blockIdx.x * 256 + threadIdx.x;
    if (i >= TOT) return;
    const bool isbf = (*flag != 0);
    int seg = 0, local = i;
#pragma unroll
    for (int s = 0; s < 12; ++s) {
        if (i >= SO[s] && i < SO[s] + SN[s]) { seg = s; local = i - SO[s]; }
    }
    const void* src = ptrs.p[seg];
    float v;
    if (isbf) v = bf2f(((const unsigned short*)src)[local]);
    else      v = ((const float*)src)[local];
    outb[i] = v;
}

// ---------------- pad pca_w (fp32 blob) -> bf16 [128][512] (K-padded with zeros)
__global__ __launch_bounds__(256) void convert_wpad(const float* __restrict__ wblob,
                                                    unsigned short* __restrict__ wpad) {
    const int i = blockIdx.x * 256 + threadIdx.x;   // 128*512 = 65536
    const int n = i >> 9, k = i & 511;
    const float v = (k < NFEAT) ? wblob[n * NFEAT + k] : 0.f;
    wpad[i] = f2bf(v);
}

// ---------------- PCA via MFMA (fp32 OR bf16 feature; inline bf16 conversion)
__global__ __launch_bounds__(256) void pca_mfma(
    const void* __restrict__ feat_raw,
    const unsigned short* __restrict__ wpad,   // [128][512] bf16
    const float* __restrict__ bias,
    const int* __restrict__ flag,
    float* __restrict__ xn,
    void* __restrict__ out_raw)
{
    __shared__ short sA[32 * 56];   // stride 56 shorts (112 B): 2-way banks = free
    __shared__ short sB[128 * 56];
    const int tid = threadIdx.x;
    const int l = tid & 63, wv = tid >> 6;
    const int m = l & 15, q = l >> 4;
    const int rt = wv >> 1, ch = wv & 1;       // row-tile, col-half
    const int r0 = blockIdx.x * 32;
    const bool isbf = (*flag != 0);

    const int arow = tid >> 3, aseg = tid & 7;

    floatx4 acc[4];
#pragma unroll
    for (int t = 0; t < 4; ++t) acc[t] = 0;

    for (int c = 0; c < 16; ++c) {
        const int k0 = c * 32;
        __syncthreads();
        {
            const int k = k0 + aseg * 4;
            uint2 v = make_uint2(0u, 0u);
            if (k < NFEAT) {
                if (isbf) {
                    v = *(const uint2*)((const unsigned short*)feat_raw +
                                        (size_t)(r0 + arow) * NFEAT + k);
                } else {
                    const float4 f = *(const float4*)((const float*)feat_raw +
                                                      (size_t)(r0 + arow) * NFEAT + k);
                    v.x = ((unsigned int)f2bf(f.y) << 16) | f2bf(f.x);
                    v.y = ((unsigned int)f2bf(f.w) << 16) | f2bf(f.z);
                }
            }
            *(uint2*)&sA[arow * 56 + aseg * 4] = v;
        }
#pragma unroll
        for (int it = 0; it < 4; ++it) {
            const int idx = tid + 256 * it;
            const int row = idx >> 3, seg = idx & 7;
            const uint2 v = *(const uint2*)(wpad + (size_t)row * 512 + k0 + seg * 4);
            *(uint2*)&sB[row * 56 + seg * 4] = v;
        }
        __syncthreads();
        const short8 af = *(const short8*)&sA[(rt * 16 + m) * 56 + q * 8];
#pragma unroll
        for (int t = 0; t < 4; ++t) {
            const short8 bf = *(const short8*)&sB[((ch * 4 + t) * 16 + m) * 56 + q * 8];
            acc[t] = __builtin_amdgcn_mfma_f32_16x16x32_bf16(af, bf, acc[t], 0, 0, 0);
        }
    }

#pragma unroll
    for (int t = 0; t < 4; ++t) {
        const int col = (ch * 4 + t) * 16 + m;
        const float bb = bias[col];
#pragma unroll
        for (int r = 0; r < 4; ++r) {
            const int grow = r0 + rt * 16 + q * 4 + r;
            const float y = fmaxf(acc[t][r] + bb, 0.f);
            if (isbf) ((unsigned short*)out_raw)[(size_t)grow * OUTC + col] = f2bf(y);
            else      ((float*)out_raw)[(size_t)grow * OUTC + col] = y;
            const float ss = sum16(y * y);
            const float invn = 1.0f / fmaxf(sqrtf(ss), 1e-12f);
            xn[(size_t)grow * 128 + col] = y * invn;
        }
    }
}

// ---------------- linear via MFMA, bf16x3 split precision (~fp32 accuracy).
template<int FIN, int FOUT>
__global__ __launch_bounds__(256) void linear_mfma(
    const float* __restrict__ xin,
    const float* __restrict__ w,
    const float* __restrict__ bias,
    float* __restrict__ xn)
{
    constexpr int KP   = ((FIN + 31) / 32) * 32;
    constexpr int NCH  = KP / 32;
    constexpr int NTIL = 2 * (FOUT / 16);
    constexpr int MT   = (NTIL + 3) / 4;
    __shared__ short sAh[32 * 56], sAl[32 * 56];
    __shared__ short sBh[FOUT * 56], sBl[FOUT * 56];
    const int tid = threadIdx.x;
    const int l = tid & 63, wv = tid >> 6;
    const int m = l & 15, q = l >> 4;
    const int n0 = blockIdx.x * 32;

    floatx4 acc[MT];
#pragma unroll
    for (int i = 0; i < MT; ++i) acc[i] = 0;

    for (int c = 0; c < NCH; ++c) {
        const int k0 = c * 32;
        __syncthreads();
        {
            const int row = tid >> 3, seg = tid & 7;
            const int k = k0 + seg * 4;
            uint2 vh = make_uint2(0u, 0u), vl = make_uint2(0u, 0u);
            if (k < FIN) {
                const float4 f = *(const float4*)(xin + (size_t)(n0 + row) * FIN + k);
                const unsigned short h0 = f2bf(f.x), h1 = f2bf(f.y);
                const unsigned short h2 = f2bf(f.z), h3 = f2bf(f.w);
                const unsigned short e0 = f2bf(f.x - bf2f(h0)), e1 = f2bf(f.y - bf2f(h1));
                const unsigned short e2 = f2bf(f.z - bf2f(h2)), e3 = f2bf(f.w - bf2f(h3));
                vh = make_uint2(((unsigned)h1 << 16) | h0, ((unsigned)h3 << 16) | h2);
                vl = make_uint2(((unsigned)e1 << 16) | e0, ((unsigned)e3 << 16) | e2);
            }
            *(uint2*)&sAh[row * 56 + seg * 4] = vh;
            *(uint2*)&sAl[row * 56 + seg * 4] = vl;
        }
        for (int idx = tid; idx < FOUT * 8; idx += 256) {
            const int row = idx >> 3, seg = idx & 7;
            const int k = k0 + seg * 4;
            uint2 vh = make_uint2(0u, 0u), vl = make_uint2(0u, 0u);
            if (k < FIN) {
                const float4 f = *(const float4*)(w + (size_t)row * FIN + k);
                const unsigned short h0 = f2bf(f.x), h1 = f2bf(f.y);
                const unsigned short h2 = f2bf(f.z), h3 = f2bf(f.w);
                const unsigned short e0 = f2bf(f.x - bf2f(h0)), e1 = f2bf(f.y - bf2f(h1));
                const unsigned short e2 = f2bf(f.z - bf2f(h2)), e3 = f2bf(f.w - bf2f(h3));
                vh = make_uint2(((unsigned)h1 << 16) | h0, ((unsigned)h3 << 16) | h2);
                vl = make_uint2(((unsigned)e1 << 16) | e0, ((unsigned)e3 << 16) | e2);
            }
            *(uint2*)&sBh[row * 56 + seg * 4] = vh;
            *(uint2*)&sBl[row * 56 + seg * 4] = vl;
        }
        __syncthreads();
#pragma unroll
        for (int ti = 0; ti < MT; ++ti) {
            const int t = wv + ti * 4;
            if (t < NTIL) {
                const int rt = t & 1, ct = t >> 1;
                const int ao = (rt * 16 + m) * 56 + q * 8;
                const int bo = (ct * 16 + m) * 56 + q * 8;
                const short8 ah = *(const short8*)&sAh[ao];
                const short8 al = *(const short8*)&sAl[ao];
                const short8 bh = *(const short8*)&sBh[bo];
                const short8 bl = *(const short8*)&sBl[bo];
                floatx4 a = acc[ti];
                a = __builtin_amdgcn_mfma_f32_16x16x32_bf16(ah, bh, a, 0, 0, 0);
                a = __builtin_amdgcn_mfma_f32_16x16x32_bf16(ah, bl, a, 0, 0, 0);
                a = __builtin_amdgcn_mfma_f32_16x16x32_bf16(al, bh, a, 0, 0, 0);
                acc[ti] = a;
            }
        }
    }
#pragma unroll
    for (int ti = 0; ti < MT; ++ti) {
        const int t = wv + ti * 4;
        if (t < NTIL) {
            const int rt = t & 1, ct = t >> 1;
            const int col = ct * 16 + m;
            const float bb = bias[col];
#pragma unroll
            for (int r = 0; r < 4; ++r) {
                const int grow = n0 + rt * 16 + q * 4 + r;
                const float y = acc[ti][r] + bb;
                const float ss = sum16(y * y);
                const float invn = __builtin_amdgcn_rsqf(fmaxf(ss, 1e-24f));
                xn[(size_t)grow * FOUT + col] = y * invn;
            }
        }
    }
}

// ---------------- routing v8a: single-wave-per-node (K<=4), z staged in LDS as
// per-lane PRIVATE storage (each z_{j,k} vector is consumed by exactly one
// lane; the butterfly shares u, never z). Register state = u(16)+x(16) floats
// -> fits the default 64-VGPR budget at 8 waves/EU. No barrier needed for z.
template<int K>
__global__ __launch_bounds__(256) void routing3(
    const float* __restrict__ xn,
    const int* __restrict__ nb,
    float* __restrict__ xout,
    void* __restrict__ out_raw,
    const int* __restrict__ flag,
    const int coloff)
{
    constexpr int KD16 = K * 16;
    __shared__ float4 zl[4][256];          // lane-linear: conflict-free b128
    const int tid = threadIdx.x;
    const int l = tid & 63;
    const int wv = tid >> 6;
    const int node = blockIdx.x * 4 + wv;
    const int j = l & 15, ks = l >> 4;
    const bool isbf = (*flag != 0);
    const int nid = nb[(size_t)node * 16 + j];
    const bool valid = (ks < K);

    v2f u[8], x[8];
    {
        const float* zsrc = xn + (size_t)nid  * KD16 + ks * 16;
        const float* xsrc = xn + (size_t)node * KD16 + ks * 16;
#pragma unroll
        for (int q = 0; q < 4; ++q) {
            float4 zq = make_float4(0.f, 0.f, 0.f, 0.f);
            float4 xq = make_float4(0.f, 0.f, 0.f, 0.f);
            if (valid) {
                zq = *(const float4*)(zsrc + q * 4);
                xq = *(const float4*)(xsrc + q * 4);
            }
            zl[q][tid] = zq;
            v2f t2 = {xq.x, xq.y}; v2f t3 = {xq.z, xq.w};
            x[2 * q] = t2; x[2 * q + 1] = t3;
            u[2 * q] = t2; u[2 * q + 1] = t3;
        }
    }
    float invn = 1.0f;

    for (int t = 0; t < 5; ++t) {
        // reload z (private LDS, 4x ds_read_b128)
        v2f zt[8];
#pragma unroll
        for (int q = 0; q < 4; ++q) {
            const float4 c = zl[q][tid];
            v2f t0 = {c.x, c.y}; v2f t1 = {c.z, c.w};
            zt[2 * q] = t0; zt[2 * q + 1] = t1;
        }
        v2f da0 = pk_mul(zt[0], u[0]);
        v2f da1 = pk_mul(zt[1], u[1]);
#pragma unroll
        for (int h = 2; h < 8; h += 2) {
            da0 = pk_fma(zt[h],     u[h],     da0);
            da1 = pk_fma(zt[h + 1], u[h + 1], da1);
        }
        const float p = valid ? (da0[0] + da0[1] + da1[0] + da1[1]) * invn : -1e4f;
        const float e = __expf(p);
        float s = e;
        s += __shfl_xor(s, 16);
        s += __shfl_xor(s, 32);
        const float es = e * __builtin_amdgcn_rcpf(s);
        const v2f ev = {es, es};
#pragma unroll
        for (int h = 0; h < 8; ++h) u[h] = pk_mul(ev, zt[h]);
        // stage-major butterfly over 16 neighbor lanes
#pragma unroll
        for (int h = 0; h < 8; ++h) { u[h][0] = dpp_add<0xB1>(u[h][0]);  u[h][1] = dpp_add<0xB1>(u[h][1]); }
#pragma unroll
        for (int h = 0; h < 8; ++h) { u[h][0] = dpp_add<0x4E>(u[h][0]);  u[h][1] = dpp_add<0x4E>(u[h][1]); }
#pragma unroll
        for (int h = 0; h < 8; ++h) { u[h][0] = dpp_add<0x141>(u[h][0]); u[h][1] = dpp_add<0x141>(u[h][1]); }
#pragma unroll
        for (int h = 0; h < 8; ++h) { u[h][0] = dpp_add<0x140>(u[h][0]); u[h][1] = dpp_add<0x140>(u[h][1]); }
        // add self term once (equivalent to summing x/16 over 16 lanes)
#pragma unroll
        for (int h = 0; h < 8; ++h) u[h] = pk_add(u[h], x[h]);
        if (t < 4) {
            v2f na0 = pk_mul(u[0], u[0]);
            v2f na1 = pk_mul(u[1], u[1]);
#pragma unroll
            for (int h = 2; h < 8; h += 2) {
                na0 = pk_fma(u[h],     u[h],     na0);
                na1 = pk_fma(u[h + 1], u[h + 1], na1);
            }
            invn = __builtin_amdgcn_rsqf(fmaxf(na0[0] + na0[1] + na1[0] + na1[1], 1e-24f));
        }
    }

#pragma unroll
    for (int h = 0; h < 8; ++h) {
        u[h][0] = fmaxf(u[h][0], 0.f);
        u[h][1] = fmaxf(u[h][1], 0.f);
    }
    if (valid && j < 4) {
        v2f a = u[0], b = u[1];
        if (j == 1)      { a = u[2]; b = u[3]; }
        else if (j == 2) { a = u[4]; b = u[5]; }
        else if (j == 3) { a = u[6]; b = u[7]; }
        const float4 w4 = make_float4(a[0], a[1], b[0], b[1]);
        *(float4*)(xout + (size_t)node * KD16 + ks * 16 + j * 4) = w4;
        const size_t ooff = (size_t)node * OUTC + coloff + ks * 16 + j * 4;
        if (isbf) {
            uint2 pk;
            pk.x = ((unsigned int)f2bf(w4.y) << 16) | f2bf(w4.x);
            pk.y = ((unsigned int)f2bf(w4.w) << 16) | f2bf(w4.z);
            *(uint2*)((unsigned short*)out_raw + ooff) = pk;
        } else {
            *(float4*)((float*)out_raw + ooff) = w4;
        }
    }
}

// ---------------- routing v8b: TWO waves per node (K in 5..8); z in private
// LDS, u+x in registers; cross-wave softmax denominator via 512-B LDS
// exchange (parity double-buffered, one barrier per iteration).
template<int K>
__global__ __launch_bounds__(256) void routing_dual(
    const float* __restrict__ xn,
    const int* __restrict__ nb,
    float* __restrict__ xout,
    void* __restrict__ out_raw,
    const int* __restrict__ flag,
    const int coloff)
{
    constexpr int KD16 = K * 16;
    __shared__ float4 zl[4][256];
    __shared__ float sden[2][2][2][16];   // [parity][node-in-block][half][j]
    const int tid = threadIdx.x;
    const int l = tid & 63, wv = tid >> 6;
    const int nib = wv >> 1, half = wv & 1;
    const int node = blockIdx.x * 2 + nib;
    const int j = l & 15, kq = l >> 4;
    const int k = half * 4 + kq;           // capsule owned by this lane
    const bool valid = (k < K);
    const bool isbf = (*flag != 0);
    const int nid = nb[(size_t)node * 16 + j];

    v2f u[8], x[8];
    {
        const float* zsrc = xn + (size_t)nid  * KD16 + k * 16;
        const float* xsrc = xn + (size_t)node * KD16 + k * 16;
#pragma unroll
        for (int q = 0; q < 4; ++q) {
            float4 zq = make_float4(0.f, 0.f, 0.f, 0.f);
            float4 xq = make_float4(0.f, 0.f, 0.f, 0.f);
            if (valid) {
                zq = *(const float4*)(zsrc + q * 4);
                xq = *(const float4*)(xsrc + q * 4);
            }
            zl[q][tid] = zq;
            v2f t2 = {xq.x, xq.y}; v2f t3 = {xq.z, xq.w};
            x[2 * q] = t2; x[2 * q + 1] = t3;
            u[2 * q] = t2; u[2 * q + 1] = t3;
        }
    }
    float invn = 1.0f;

    for (int t = 0; t < 5; ++t) {
        v2f zt[8];
#pragma unroll
        for (int q = 0; q < 4; ++q) {
            const float4 c = zl[q][tid];
            v2f t0 = {c.x, c.y}; v2f t1 = {c.z, c.w};
            zt[2 * q] = t0; zt[2 * q + 1] = t1;
        }
        v2f da0 = pk_mul(zt[0], u[0]);
        v2f da1 = pk_mul(zt[1], u[1]);
#pragma unroll
        for (int h = 2; h < 8; h += 2) {
            da0 = pk_fma(zt[h],     u[h],     da0);
            da1 = pk_fma(zt[h + 1], u[h + 1], da1);
        }
        const float p = valid ? (da0[0] + da0[1] + da1[0] + da1[1]) * invn : -1e4f;
        const float e = __expf(p);
        // partial softmax denominator over this wave's 4 capsules
        float s = e;
        s += __shfl_xor(s, 16);
        s += __shfl_xor(s, 32);
        // cross-wave: exchange half-partials through LDS (parity double-buffer)
        if (l < 16) sden[t & 1][nib][half][j] = s;
        __syncthreads();
        s += sden[t & 1][nib][half ^ 1][j];
        const float es = e * __builtin_amdgcn_rcpf(s);
        const v2f ev = {es, es};
#pragma unroll
        for (int h = 0; h < 8; ++h) u[h] = pk_mul(ev, zt[h]);
        // stage-major butterfly over 16 neighbor lanes
#pragma unroll
        for (int h = 0; h < 8; ++h) { u[h][0] = dpp_add<0xB1>(u[h][0]);  u[h][1] = dpp_add<0xB1>(u[h][1]); }
#pragma unroll
        for (int h = 0; h < 8; ++h) { u[h][0] = dpp_add<0x4E>(u[h][0]);  u[h][1] = dpp_add<0x4E>(u[h][1]); }
#pragma unroll
        for (int h = 0; h < 8; ++h) { u[h][0] = dpp_add<0x141>(u[h][0]); u[h][1] = dpp_add<0x141>(u[h][1]); }
#pragma unroll
        for (int h = 0; h < 8; ++h) { u[h][0] = dpp_add<0x140>(u[h][0]); u[h][1] = dpp_add<0x140>(u[h][1]); }
        // add self term once
#pragma unroll
        for (int h = 0; h < 8; ++h) u[h] = pk_add(u[h], x[h]);
        if (t < 4) {
            v2f na0 = pk_mul(u[0], u[0]);
            v2f na1 = pk_mul(u[1], u[1]);
#pragma unroll
            for (int h = 2; h < 8; h += 2) {
                na0 = pk_fma(u[h],     u[h],     na0);
                na1 = pk_fma(u[h + 1], u[h + 1], na1);
            }
            invn = __builtin_amdgcn_rsqf(fmaxf(na0[0] + na0[1] + na1[0] + na1[1], 1e-24f));
        }
    }

#pragma unroll
    for (int h = 0; h < 8; ++h) {
        u[h][0] = fmaxf(u[h][0], 0.f);
        u[h][1] = fmaxf(u[h][1], 0.f);
    }
    if (valid && j < 4) {
        v2f a = u[0], b = u[1];
        if (j == 1)      { a = u[2]; b = u[3]; }
        else if (j == 2) { a = u[4]; b = u[5]; }
        else if (j == 3) { a = u[6]; b = u[7]; }
        const float4 w4 = make_float4(a[0], a[1], b[0], b[1]);
        *(float4*)(xout + (size_t)node * KD16 + k * 16 + j * 4) = w4;
        const size_t ooff = (size_t)node * OUTC + coloff + k * 16 + j * 4;
        if (isbf) {
            uint2 pk;
            pk.x = ((unsigned int)f2bf(w4.y) << 16) | f2bf(w4.x);
            pk.y = ((unsigned int)f2bf(w4.w) << 16) | f2bf(w4.z);
            *(uint2*)((unsigned short*)out_raw + ooff) = pk;
        } else {
            *(float4*)((float*)out_raw + ooff) = w4;
        }
    }
}

extern "C" void kernel_launch(void* const* d_in, const int* in_sizes, int n_in,
                              void* d_out, int out_size, void* d_ws, size_t ws_size,
                              hipStream_t stream) {
    const int* nbid = (const int*)d_in[1];

    int*            flag  = (int*)d_ws;
    float*          wblob = (float*)((char*)d_ws + 16);
    unsigned short* wpad  = (unsigned short*)((char*)d_ws + (448 << 10));
    float*          xn    = (float*)((char*)d_ws + (1 << 20));
    float*          xc    = xn + (size_t)NNODES * 128;

    float* pw = wblob +      0; float* pb = wblob +  64000;
    float* w1 = wblob +  64128; float* b1 = wblob +  78464;
    float* w2 = wblob +  78576; float* b2 = wblob +  89328;
    float* w3 = wblob +  89424; float* b3 = wblob +  97104;
    float* w4 = wblob +  97184; float* b4 = wblob + 102304;
    float* w5 = wblob + 102368; float* b5 = wblob + 105440;

    hipLaunchKernelGGL(detect_kernel, dim3(1), dim3(64), 0, stream,
                       (const unsigned short*)d_in[0], flag);

    WPtrs wp;
    for (int i = 0; i < 12; ++i) wp.p[i] = d_in[i + 2];
    hipLaunchKernelGGL(convert_weights, dim3(413), dim3(256), 0, stream, wp, flag, wblob);
    hipLaunchKernelGGL(convert_wpad, dim3(256), dim3(256), 0, stream, pw, wpad);

    hipLaunchKernelGGL(pca_mfma, dim3(NNODES / 32), dim3(256), 0, stream,
                       d_in[0], wpad, pb, flag, xn, d_out);

    const int dgrid = NNODES / 2;   // routing_dual: 2 nodes/block
    const int rgrid = NNODES / 4;   // routing3: 4 nodes/block
    const int lgrid = NNODES / 32;

    hipLaunchKernelGGL((routing_dual<8>), dim3(dgrid), dim3(256), 0, stream,
                       xn, nbid, xc, d_out, flag, 128);
    hipLaunchKernelGGL((linear_mfma<128, 112>), dim3(lgrid), dim3(256), 0, stream,
                       xc, w1, b1, xn);

    hipLaunchKernelGGL((routing_dual<7>), dim3(dgrid), dim3(256), 0, stream,
                       xn, nbid, xc, d_out, flag, 256);
    hipLaunchKernelGGL((linear_mfma<112, 96>), dim3(lgrid), dim3(256), 0, stream,
                       xc, w2, b2, xn);

    hipLaunchKernelGGL((routing_dual<6>), dim3(dgrid), dim3(256), 0, stream,
                       xn, nbid, xc, d_out, flag, 368);
    hipLaunchKernelGGL((linear_mfma<96, 80>), dim3(lgrid), dim3(256), 0, stream,
                       xc, w3, b3, xn);

    hipLaunchKernelGGL((routing_dual<5>), dim3(dgrid), dim3(256), 0, stream,
                       xn, nbid, xc, d_out, flag, 464);
    hipLaunchKernelGGL((linear_mfma<80, 64>), dim3(lgrid), dim3(256), 0, stream,
                       xc, w4, b4, xn);

    hipLaunchKernelGGL((routing3<4>), dim3(rgrid), dim3(256), 0, stream,
                       xn, nbid, xc, d_out, flag, 544);
    hipLaunchKernelGGL((linear_mfma<64, 48>), dim3(lgrid), dim3(256), 0, stream,
                       xc, w5, b5, xn);

    hipLaunchKernelGGL((routing3<3>), dim3(rgrid), dim3(256), 0, stream,
                       xn, nbid, xc, d_out, flag, 608);
}

// Round 6
// 452.692 us; speedup vs baseline: 1.2062x; 1.1060x over previous
//
#include <hip/hip_runtime.h>
#include <hip/hip_bf16.h>
#include <cstdint>
#include <cstddef>

#define NNODES 20000
#define MNB    16
#define NFEAT  500
#define OUTC   656

typedef short short8 __attribute__((ext_vector_type(8)));
typedef float floatx4 __attribute__((ext_vector_type(4)));
typedef float v2f __attribute__((ext_vector_type(2)));

__device__ __forceinline__ float bf2f(unsigned int h) {
    union { unsigned int u; float f; } v; v.u = h << 16; return v.f;
}
__device__ __forceinline__ unsigned short f2bf(float f) {
    union { float f; unsigned int u; } v; v.f = f;
    unsigned int u = v.u;
    u += 0x7FFFu + ((u >> 16) & 1u);   // RNE
    return (unsigned short)(u >> 16);
}

// packed fp32 math (2x rate on CDNA): explicit VOP3P via asm.
__device__ __forceinline__ v2f pk_mul(v2f a, v2f b) {
    v2f d;
    asm("v_pk_mul_f32 %0, %1, %2 op_sel:[0,0] op_sel_hi:[1,1]"
        : "=v"(d) : "v"(a), "v"(b));
    return d;
}
__device__ __forceinline__ v2f pk_fma(v2f a, v2f b, v2f c) {
    v2f d;
    asm("v_pk_fma_f32 %0, %1, %2, %3 op_sel:[0,0,0] op_sel_hi:[1,1,1]"
        : "=v"(d) : "v"(a), "v"(b), "v"(c));
    return d;
}
__device__ __forceinline__ v2f pk_add(v2f a, v2f b) {
    v2f d;
    asm("v_pk_add_f32 %0, %1, %2 op_sel:[0,0] op_sel_hi:[1,1]"
        : "=v"(d) : "v"(a), "v"(b));
    return d;
}

// DPP helpers. 0xB1 quad xor1, 0x4E quad xor2, 0x141 half-mirror (^7),
// 0x140 mirror (^15), 0x128 row_ror:8 (rot8 on 16 == xor8).
template<int CTRL>
__device__ __forceinline__ float dpp_add(float v) {
    const int o = __builtin_amdgcn_update_dpp(0, __float_as_int(v), CTRL, 0xF, 0xF, true);
    return v + __int_as_float(o);
}
__device__ __forceinline__ float sum16(float v) {
    v = dpp_add<0xB1>(v);
    v = dpp_add<0x4E>(v);
    v = dpp_add<0x141>(v);
    v = dpp_add<0x140>(v);
    return v;
}

// ---------------- dtype probe
__global__ __launch_bounds__(64) void detect_kernel(const unsigned short* __restrict__ fx,
                                                    int* __restrict__ flag) {
    const int tid = threadIdx.x;
    const unsigned short s = fx[2 * tid];
    const int e = (s >> 7) & 0xFF;
    const bool ok = (e >= 100 && e <= 140);
    const unsigned long long m = __ballot(ok);
    if (tid == 0) *flag = (__popcll(m) >= 32) ? 1 : 0;
}

// ---------------- convert all weights/biases to one fp32 blob in ws
struct WPtrs { const void* p[12]; };

__global__ __launch_bounds__(256) void convert_weights(WPtrs ptrs, const int* __restrict__ flag,
                                                       float* __restrict__ outb) {
    constexpr int SN[12] = {64000,128,14336,112,10752,96,7680,80,5120,64,3072,48};
    constexpr int SO[12] = {0,64000,64128,78464,78576,89328,89424,97104,97184,102304,102368,105440};
    constexpr int TOT = 105488;
    const int i = blockIdx.x * 256 + threadIdx.x;
    if (i >= TOT) return;
    const bool isbf = (*flag != 0);
    int seg = 0, local = i;
#pragma unroll
    for (int s = 0; s < 12; ++s) {
        if (i >= SO[s] && i < SO[s] + SN[s]) { seg = s; local = i - SO[s]; }
    }
    const void* src = ptrs.p[seg];
    float v;
    if (isbf) v = bf2f(((const unsigned short*)src)[local]);
    else      v = ((const float*)src)[local];
    outb[i] = v;
}

// ---------------- pad pca_w (fp32 blob) -> bf16 [128][512] (K-padded with zeros)
__global__ __launch_bounds__(256) void convert_wpad(const float* __restrict__ wblob,
                                                    unsigned short* __restrict__ wpad) {
    const int i = blockIdx.x * 256 + threadIdx.x;   // 128*512 = 65536
    const int n = i >> 9, k = i & 511;
    const float v = (k < NFEAT) ? wblob[n * NFEAT + k] : 0.f;
    wpad[i] = f2bf(v);
}

// ---------------- PCA via MFMA (fp32 OR bf16 feature; inline bf16 conversion)
__global__ __launch_bounds__(256) void pca_mfma(
    const void* __restrict__ feat_raw,
    const unsigned short* __restrict__ wpad,   // [128][512] bf16
    const float* __restrict__ bias,
    const int* __restrict__ flag,
    float* __restrict__ xn,
    void* __restrict__ out_raw)
{
    __shared__ short sA[32 * 56];   // stride 56 shorts (112 B): 2-way banks = free
    __shared__ short sB[128 * 56];
    const int tid = threadIdx.x;
    const int l = tid & 63, wv = tid >> 6;
    const int m = l & 15, q = l >> 4;
    const int rt = wv >> 1, ch = wv & 1;       // row-tile, col-half
    const int r0 = blockIdx.x * 32;
    const bool isbf = (*flag != 0);

    const int arow = tid >> 3, aseg = tid & 7;

    floatx4 acc[4];
#pragma unroll
    for (int t = 0; t < 4; ++t) acc[t] = 0;

    for (int c = 0; c < 16; ++c) {
        const int k0 = c * 32;
        __syncthreads();
        {
            const int k = k0 + aseg * 4;
            uint2 v = make_uint2(0u, 0u);
            if (k < NFEAT) {
                if (isbf) {
                    v = *(const uint2*)((const unsigned short*)feat_raw +
                                        (size_t)(r0 + arow) * NFEAT + k);
                } else {
                    const float4 f = *(const float4*)((const float*)feat_raw +
                                                      (size_t)(r0 + arow) * NFEAT + k);
                    v.x = ((unsigned int)f2bf(f.y) << 16) | f2bf(f.x);
                    v.y = ((unsigned int)f2bf(f.w) << 16) | f2bf(f.z);
                }
            }
            *(uint2*)&sA[arow * 56 + aseg * 4] = v;
        }
#pragma unroll
        for (int it = 0; it < 4; ++it) {
            const int idx = tid + 256 * it;
            const int row = idx >> 3, seg = idx & 7;
            const uint2 v = *(const uint2*)(wpad + (size_t)row * 512 + k0 + seg * 4);
            *(uint2*)&sB[row * 56 + seg * 4] = v;
        }
        __syncthreads();
        const short8 af = *(const short8*)&sA[(rt * 16 + m) * 56 + q * 8];
#pragma unroll
        for (int t = 0; t < 4; ++t) {
            const short8 bf = *(const short8*)&sB[((ch * 4 + t) * 16 + m) * 56 + q * 8];
            acc[t] = __builtin_amdgcn_mfma_f32_16x16x32_bf16(af, bf, acc[t], 0, 0, 0);
        }
    }

#pragma unroll
    for (int t = 0; t < 4; ++t) {
        const int col = (ch * 4 + t) * 16 + m;
        const float bb = bias[col];
#pragma unroll
        for (int r = 0; r < 4; ++r) {
            const int grow = r0 + rt * 16 + q * 4 + r;
            const float y = fmaxf(acc[t][r] + bb, 0.f);
            if (isbf) ((unsigned short*)out_raw)[(size_t)grow * OUTC + col] = f2bf(y);
            else      ((float*)out_raw)[(size_t)grow * OUTC + col] = y;
            const float ss = sum16(y * y);
            const float invn = 1.0f / fmaxf(sqrtf(ss), 1e-12f);
            xn[(size_t)grow * 128 + col] = y * invn;
        }
    }
}

// ---------------- linear via MFMA, bf16x3 split precision (~fp32 accuracy).
template<int FIN, int FOUT>
__global__ __launch_bounds__(256) void linear_mfma(
    const float* __restrict__ xin,
    const float* __restrict__ w,
    const float* __restrict__ bias,
    float* __restrict__ xn)
{
    constexpr int KP   = ((FIN + 31) / 32) * 32;
    constexpr int NCH  = KP / 32;
    constexpr int NTIL = 2 * (FOUT / 16);
    constexpr int MT   = (NTIL + 3) / 4;
    __shared__ short sAh[32 * 56], sAl[32 * 56];
    __shared__ short sBh[FOUT * 56], sBl[FOUT * 56];
    const int tid = threadIdx.x;
    const int l = tid & 63, wv = tid >> 6;
    const int m = l & 15, q = l >> 4;
    const int n0 = blockIdx.x * 32;

    floatx4 acc[MT];
#pragma unroll
    for (int i = 0; i < MT; ++i) acc[i] = 0;

    for (int c = 0; c < NCH; ++c) {
        const int k0 = c * 32;
        __syncthreads();
        {
            const int row = tid >> 3, seg = tid & 7;
            const int k = k0 + seg * 4;
            uint2 vh = make_uint2(0u, 0u), vl = make_uint2(0u, 0u);
            if (k < FIN) {
                const float4 f = *(const float4*)(xin + (size_t)(n0 + row) * FIN + k);
                const unsigned short h0 = f2bf(f.x), h1 = f2bf(f.y);
                const unsigned short h2 = f2bf(f.z), h3 = f2bf(f.w);
                const unsigned short e0 = f2bf(f.x - bf2f(h0)), e1 = f2bf(f.y - bf2f(h1));
                const unsigned short e2 = f2bf(f.z - bf2f(h2)), e3 = f2bf(f.w - bf2f(h3));
                vh = make_uint2(((unsigned)h1 << 16) | h0, ((unsigned)h3 << 16) | h2);
                vl = make_uint2(((unsigned)e1 << 16) | e0, ((unsigned)e3 << 16) | e2);
            }
            *(uint2*)&sAh[row * 56 + seg * 4] = vh;
            *(uint2*)&sAl[row * 56 + seg * 4] = vl;
        }
        for (int idx = tid; idx < FOUT * 8; idx += 256) {
            const int row = idx >> 3, seg = idx & 7;
            const int k = k0 + seg * 4;
            uint2 vh = make_uint2(0u, 0u), vl = make_uint2(0u, 0u);
            if (k < FIN) {
                const float4 f = *(const float4*)(w + (size_t)row * FIN + k);
                const unsigned short h0 = f2bf(f.x), h1 = f2bf(f.y);
                const unsigned short h2 = f2bf(f.z), h3 = f2bf(f.w);
                const unsigned short e0 = f2bf(f.x - bf2f(h0)), e1 = f2bf(f.y - bf2f(h1));
                const unsigned short e2 = f2bf(f.z - bf2f(h2)), e3 = f2bf(f.w - bf2f(h3));
                vh = make_uint2(((unsigned)h1 << 16) | h0, ((unsigned)h3 << 16) | h2);
                vl = make_uint2(((unsigned)e1 << 16) | e0, ((unsigned)e3 << 16) | e2);
            }
            *(uint2*)&sBh[row * 56 + seg * 4] = vh;
            *(uint2*)&sBl[row * 56 + seg * 4] = vl;
        }
        __syncthreads();
#pragma unroll
        for (int ti = 0; ti < MT; ++ti) {
            const int t = wv + ti * 4;
            if (t < NTIL) {
                const int rt = t & 1, ct = t >> 1;
                const int ao = (rt * 16 + m) * 56 + q * 8;
                const int bo = (ct * 16 + m) * 56 + q * 8;
                const short8 ah = *(const short8*)&sAh[ao];
                const short8 al = *(const short8*)&sAl[ao];
                const short8 bh = *(const short8*)&sBh[bo];
                const short8 bl = *(const short8*)&sBl[bo];
                floatx4 a = acc[ti];
                a = __builtin_amdgcn_mfma_f32_16x16x32_bf16(ah, bh, a, 0, 0, 0);
                a = __builtin_amdgcn_mfma_f32_16x16x32_bf16(ah, bl, a, 0, 0, 0);
                a = __builtin_amdgcn_mfma_f32_16x16x32_bf16(al, bh, a, 0, 0, 0);
                acc[ti] = a;
            }
        }
    }
#pragma unroll
    for (int ti = 0; ti < MT; ++ti) {
        const int t = wv + ti * 4;
        if (t < NTIL) {
            const int rt = t & 1, ct = t >> 1;
            const int col = ct * 16 + m;
            const float bb = bias[col];
#pragma unroll
            for (int r = 0; r < 4; ++r) {
                const int grow = n0 + rt * 16 + q * 4 + r;
                const float y = acc[ti][r] + bb;
                const float ss = sum16(y * y);
                const float invn = __builtin_amdgcn_rsqf(fmaxf(ss, 1e-24f));
                xn[(size_t)grow * FOUT + col] = y * invn;
            }
        }
    }
}

// ---------------- routing v9: ONE wave per node (K 5..8) / TWO nodes per wave
// (K 3..4). lane = m(3b) | k(2-3b) | [nsub]. Each lane owns capsule k of
// neighbors m and m+8, 16 dims in registers during the iteration.
//  - dot over d: in-register (no cross-lane)
//  - softmax over k: DPP row_ror:8 (xor8) + shfl_xor 16 [+ 32] -- NO barrier
//  - neighbor sum: in-register pair + 3-stage DPP butterfly over 8 m-lanes
//  - z in private LDS (read once/iter); x re-read from L2 after butterfly
// Register state ~56 VGPR -> fits the 64-VGPR/8-wave budget by construction.
template<int K, int NPW>
__global__ __launch_bounds__(256) void routing_v9(
    const float* __restrict__ xn,
    const int* __restrict__ nb,
    float* __restrict__ xout,
    void* __restrict__ out_raw,
    const int* __restrict__ flag,
    const int coloff)
{
    constexpr int KD16 = K * 16;
    __shared__ float4 zl[8][256];
    const int tid = threadIdx.x;
    const int l = tid & 63, wv = tid >> 6;
    const int m = l & 7;
    const int k = (l >> 3) & (NPW == 2 ? 3 : 7);
    const int nsub = (NPW == 2) ? (l >> 5) : 0;
    const int node = blockIdx.x * (4 * NPW) + wv * NPW + nsub;
    const bool kv = (k < K);
    const bool isbf = (*flag != 0);
    const int nid0 = nb[(size_t)node * 16 + m];
    const int nid1 = nb[(size_t)node * 16 + m + 8];

    v2f u[8];
    {
        const float* z0p = xn + (size_t)nid0 * KD16 + k * 16;
        const float* z1p = xn + (size_t)nid1 * KD16 + k * 16;
        const float* xp  = xn + (size_t)node * KD16 + k * 16;
#pragma unroll
        for (int q = 0; q < 4; ++q) {
            float4 a = make_float4(0.f, 0.f, 0.f, 0.f);
            float4 b = a, c = a;
            if (kv) {
                a = *(const float4*)(z0p + q * 4);
                b = *(const float4*)(z1p + q * 4);
                c = *(const float4*)(xp  + q * 4);
            }
            zl[q][tid]     = a;
            zl[4 + q][tid] = b;
            v2f t0 = {c.x, c.y}; v2f t1 = {c.z, c.w};
            u[2 * q] = t0; u[2 * q + 1] = t1;
        }
    }
    float invn = 1.0f;

    for (int t = 0; t < 5; ++t) {
        // z for both neighbors (private LDS, 8x ds_read_b128, read once)
        v2f z0[8], z1[8];
#pragma unroll
        for (int q = 0; q < 4; ++q) {
            const float4 a = zl[q][tid];
            const float4 b = zl[4 + q][tid];
            z0[2 * q] = (v2f){a.x, a.y}; z0[2 * q + 1] = (v2f){a.z, a.w};
            z1[2 * q] = (v2f){b.x, b.y}; z1[2 * q + 1] = (v2f){b.z, b.w};
        }
        // agreement scores (two interleaved packed chains)
        v2f d0 = pk_mul(z0[0], u[0]);
        v2f d1 = pk_mul(z1[0], u[0]);
#pragma unroll
        for (int h = 1; h < 8; ++h) {
            d0 = pk_fma(z0[h], u[h], d0);
            d1 = pk_fma(z1[h], u[h], d1);
        }
        const float p0 = kv ? (d0[0] + d0[1]) * invn : -1e4f;
        const float p1 = kv ? (d1[0] + d1[1]) * invn : -1e4f;
        float e0 = __expf(p0), e1 = __expf(p1);
        // softmax denominator over k: xor8 (DPP rot8) [+ xor16 [+ xor32]]
        float s0 = dpp_add<0x128>(e0);
        float s1 = dpp_add<0x128>(e1);
        s0 += __shfl_xor(s0, 16);
        s1 += __shfl_xor(s1, 16);
        if (NPW == 1) {
            s0 += __shfl_xor(s0, 32);
            s1 += __shfl_xor(s1, 32);
        }
        e0 *= __builtin_amdgcn_rcpf(s0);
        e1 *= __builtin_amdgcn_rcpf(s1);
        const v2f ev0 = {e0, e0}, ev1 = {e1, e1};
        // aggregate this lane's two neighbors
#pragma unroll
        for (int h = 0; h < 8; ++h)
            u[h] = pk_fma(ev1, z1[h], pk_mul(ev0, z0[h]));
        // sum over 8 m-lanes: xor1, xor2, ^7 (stage-major DPP)
#pragma unroll
        for (int h = 0; h < 8; ++h) { u[h][0] = dpp_add<0xB1>(u[h][0]);  u[h][1] = dpp_add<0xB1>(u[h][1]); }
#pragma unroll
        for (int h = 0; h < 8; ++h) { u[h][0] = dpp_add<0x4E>(u[h][0]);  u[h][1] = dpp_add<0x4E>(u[h][1]); }
#pragma unroll
        for (int h = 0; h < 8; ++h) { u[h][0] = dpp_add<0x141>(u[h][0]); u[h][1] = dpp_add<0x141>(u[h][1]); }
        // + self term x (re-read from L2; z regs are dead by now)
        {
            const float* xp = xn + (size_t)node * KD16 + k * 16;
#pragma unroll
            for (int q = 0; q < 4; ++q) {
                float4 c = make_float4(0.f, 0.f, 0.f, 0.f);
                if (kv) c = *(const float4*)(xp + q * 4);
                u[2 * q]     = pk_add(u[2 * q],     (v2f){c.x, c.y});
                u[2 * q + 1] = pk_add(u[2 * q + 1], (v2f){c.z, c.w});
            }
        }
        // capsule norm (d fully in-register: no cross-lane)
        if (t < 4) {
            v2f n0 = pk_mul(u[0], u[0]);
            v2f n1 = pk_mul(u[1], u[1]);
#pragma unroll
            for (int h = 2; h < 8; h += 2) {
                n0 = pk_fma(u[h],     u[h],     n0);
                n1 = pk_fma(u[h + 1], u[h + 1], n1);
            }
            invn = __builtin_amdgcn_rsqf(fmaxf(n0[0] + n0[1] + n1[0] + n1[1], 1e-24f));
        }
    }

    // relu + store (u replicated across the 8 m-lanes; m<4 write 4 dims each)
#pragma unroll
    for (int h = 0; h < 8; ++h) {
        u[h][0] = fmaxf(u[h][0], 0.f);
        u[h][1] = fmaxf(u[h][1], 0.f);
    }
    if (kv && m < 4) {
        v2f a = u[0], b = u[1];
        if (m == 1)      { a = u[2]; b = u[3]; }
        else if (m == 2) { a = u[4]; b = u[5]; }
        else if (m == 3) { a = u[6]; b = u[7]; }
        const float4 w4 = make_float4(a[0], a[1], b[0], b[1]);
        *(float4*)(xout + (size_t)node * KD16 + k * 16 + m * 4) = w4;
        const size_t ooff = (size_t)node * OUTC + coloff + k * 16 + m * 4;
        if (isbf) {
            uint2 pk;
            pk.x = ((unsigned int)f2bf(w4.y) << 16) | f2bf(w4.x);
            pk.y = ((unsigned int)f2bf(w4.w) << 16) | f2bf(w4.z);
            *(uint2*)((unsigned short*)out_raw + ooff) = pk;
        } else {
            *(float4*)((float*)out_raw + ooff) = w4;
        }
    }
}

extern "C" void kernel_launch(void* const* d_in, const int* in_sizes, int n_in,
                              void* d_out, int out_size, void* d_ws, size_t ws_size,
                              hipStream_t stream) {
    const int* nbid = (const int*)d_in[1];

    int*            flag  = (int*)d_ws;
    float*          wblob = (float*)((char*)d_ws + 16);
    unsigned short* wpad  = (unsigned short*)((char*)d_ws + (448 << 10));
    float*          xn    = (float*)((char*)d_ws + (1 << 20));
    float*          xc    = xn + (size_t)NNODES * 128;

    float* pw = wblob +      0; float* pb = wblob +  64000;
    float* w1 = wblob +  64128; float* b1 = wblob +  78464;
    float* w2 = wblob +  78576; float* b2 = wblob +  89328;
    float* w3 = wblob +  89424; float* b3 = wblob +  97104;
    float* w4 = wblob +  97184; float* b4 = wblob + 102304;
    float* w5 = wblob + 102368; float* b5 = wblob + 105440;

    hipLaunchKernelGGL(detect_kernel, dim3(1), dim3(64), 0, stream,
                       (const unsigned short*)d_in[0], flag);

    WPtrs wp;
    for (int i = 0; i < 12; ++i) wp.p[i] = d_in[i + 2];
    hipLaunchKernelGGL(convert_weights, dim3(413), dim3(256), 0, stream, wp, flag, wblob);
    hipLaunchKernelGGL(convert_wpad, dim3(256), dim3(256), 0, stream, pw, wpad);

    hipLaunchKernelGGL(pca_mfma, dim3(NNODES / 32), dim3(256), 0, stream,
                       d_in[0], wpad, pb, flag, xn, d_out);

    const int g1 = NNODES / 4;   // NPW=1: 4 nodes/block
    const int g2 = NNODES / 8;   // NPW=2: 8 nodes/block
    const int lgrid = NNODES / 32;

    hipLaunchKernelGGL((routing_v9<8, 1>), dim3(g1), dim3(256), 0, stream,
                       xn, nbid, xc, d_out, flag, 128);
    hipLaunchKernelGGL((linear_mfma<128, 112>), dim3(lgrid), dim3(256), 0, stream,
                       xc, w1, b1, xn);

    hipLaunchKernelGGL((routing_v9<7, 1>), dim3(g1), dim3(256), 0, stream,
                       xn, nbid, xc, d_out, flag, 256);
    hipLaunchKernelGGL((linear_mfma<112, 96>), dim3(lgrid), dim3(256), 0, stream,
                       xc, w2, b2, xn);

    hipLaunchKernelGGL((routing_v9<6, 1>), dim3(g1), dim3(256), 0, stream,
                       xn, nbid, xc, d_out, flag, 368);
    hipLaunchKernelGGL((linear_mfma<96, 80>), dim3(lgrid), dim3(256), 0, stream,
                       xc, w3, b3, xn);

    hipLaunchKernelGGL((routing_v9<5, 1>), dim3(g1), dim3(256), 0, stream,
                       xn, nbid, xc, d_out, flag, 464);
    hipLaunchKernelGGL((linear_mfma<80, 64>), dim3(lgrid), dim3(256), 0, stream,
                       xc, w4, b4, xn);

    hipLaunchKernelGGL((routing_v9<4, 2>), dim3(g2), dim3(256), 0, stream,
                       xn, nbid, xc, d_out, flag, 544);
    hipLaunchKernelGGL((linear_mfma<64, 48>), dim3(lgrid), dim3(256), 0, stream,
                       xc, w5, b5, xn);

    hipLaunchKernelGGL((routing_v9<3, 2>), dim3(g2), dim3(256), 0, stream,
                       xn, nbid, xc, d_out, flag, 608);
}

// Round 7
// 428.848 us; speedup vs baseline: 1.2733x; 1.0556x over previous
//
#include <hip/hip_runtime.h>
#include <hip/hip_bf16.h>
#include <cstdint>
#include <cstddef>

#define NNODES 20000
#define MNB    16
#define NFEAT  500
#define OUTC   656

typedef short short8 __attribute__((ext_vector_type(8)));
typedef float floatx4 __attribute__((ext_vector_type(4)));
typedef float v2f __attribute__((ext_vector_type(2)));

__device__ __forceinline__ float bf2f(unsigned int h) {
    union { unsigned int u; float f; } v; v.u = h << 16; return v.f;
}
__device__ __forceinline__ unsigned short f2bf(float f) {
    union { float f; unsigned int u; } v; v.f = f;
    unsigned int u = v.u;
    u += 0x7FFFu + ((u >> 16) & 1u);   // RNE
    return (unsigned short)(u >> 16);
}

// packed fp32 math (2x rate on CDNA): explicit VOP3P via asm.
__device__ __forceinline__ v2f pk_mul(v2f a, v2f b) {
    v2f d;
    asm("v_pk_mul_f32 %0, %1, %2 op_sel:[0,0] op_sel_hi:[1,1]"
        : "=v"(d) : "v"(a), "v"(b));
    return d;
}
__device__ __forceinline__ v2f pk_fma(v2f a, v2f b, v2f c) {
    v2f d;
    asm("v_pk_fma_f32 %0, %1, %2, %3 op_sel:[0,0,0] op_sel_hi:[1,1,1]"
        : "=v"(d) : "v"(a), "v"(b), "v"(c));
    return d;
}
__device__ __forceinline__ v2f pk_add(v2f a, v2f b) {
    v2f d;
    asm("v_pk_add_f32 %0, %1, %2 op_sel:[0,0] op_sel_hi:[1,1]"
        : "=v"(d) : "v"(a), "v"(b));
    return d;
}

// Opaque register pin: output of asm cannot be rematerialized from memory.
#define PIN(x) asm volatile("" : "+v"(x))

// DPP helpers. 0xB1 quad xor1, 0x4E quad xor2, 0x141 half-mirror (^7),
// 0x140 mirror (^15), 0x128 row_ror:8 (rot8 on 16 == xor8).
template<int CTRL>
__device__ __forceinline__ float dpp_add(float v) {
    const int o = __builtin_amdgcn_update_dpp(0, __float_as_int(v), CTRL, 0xF, 0xF, true);
    return v + __int_as_float(o);
}
__device__ __forceinline__ float sum16(float v) {
    v = dpp_add<0xB1>(v);
    v = dpp_add<0x4E>(v);
    v = dpp_add<0x141>(v);
    v = dpp_add<0x140>(v);
    return v;
}

// ---------------- dtype probe
__global__ __launch_bounds__(64) void detect_kernel(const unsigned short* __restrict__ fx,
                                                    int* __restrict__ flag) {
    const int tid = threadIdx.x;
    const unsigned short s = fx[2 * tid];
    const int e = (s >> 7) & 0xFF;
    const bool ok = (e >= 100 && e <= 140);
    const unsigned long long m = __ballot(ok);
    if (tid == 0) *flag = (__popcll(m) >= 32) ? 1 : 0;
}

// ---------------- convert all weights/biases to one fp32 blob in ws
struct WPtrs { const void* p[12]; };

__global__ __launch_bounds__(256) void convert_weights(WPtrs ptrs, const int* __restrict__ flag,
                                                       float* __restrict__ outb) {
    constexpr int SN[12] = {64000,128,14336,112,10752,96,7680,80,5120,64,3072,48};
    constexpr int SO[12] = {0,64000,64128,78464,78576,89328,89424,97104,97184,102304,102368,105440};
    constexpr int TOT = 105488;
    const int i = blockIdx.x * 256 + threadIdx.x;
    if (i >= TOT) return;
    const bool isbf = (*flag != 0);
    int seg = 0, local = i;
#pragma unroll
    for (int s = 0; s < 12; ++s) {
        if (i >= SO[s] && i < SO[s] + SN[s]) { seg = s; local = i - SO[s]; }
    }
    const void* src = ptrs.p[seg];
    float v;
    if (isbf) v = bf2f(((const unsigned short*)src)[local]);
    else      v = ((const float*)src)[local];
    outb[i] = v;
}

// ---------------- pad pca_w (fp32 blob) -> bf16 [128][512] (K-padded with zeros)
__global__ __launch_bounds__(256) void convert_wpad(const float* __restrict__ wblob,
                                                    unsigned short* __restrict__ wpad) {
    const int i = blockIdx.x * 256 + threadIdx.x;   // 128*512 = 65536
    const int n = i >> 9, k = i & 511;
    const float v = (k < NFEAT) ? wblob[n * NFEAT + k] : 0.f;
    wpad[i] = f2bf(v);
}

// ---------------- PCA via MFMA (fp32 OR bf16 feature; inline bf16 conversion)
__global__ __launch_bounds__(256) void pca_mfma(
    const void* __restrict__ feat_raw,
    const unsigned short* __restrict__ wpad,   // [128][512] bf16
    const float* __restrict__ bias,
    const int* __restrict__ flag,
    float* __restrict__ xn,
    void* __restrict__ out_raw)
{
    __shared__ short sA[32 * 56];   // stride 56 shorts (112 B): 2-way banks = free
    __shared__ short sB[128 * 56];
    const int tid = threadIdx.x;
    const int l = tid & 63, wv = tid >> 6;
    const int m = l & 15, q = l >> 4;
    const int rt = wv >> 1, ch = wv & 1;       // row-tile, col-half
    const int r0 = blockIdx.x * 32;
    const bool isbf = (*flag != 0);

    const int arow = tid >> 3, aseg = tid & 7;

    floatx4 acc[4];
#pragma unroll
    for (int t = 0; t < 4; ++t) acc[t] = 0;

    for (int c = 0; c < 16; ++c) {
        const int k0 = c * 32;
        __syncthreads();
        {
            const int k = k0 + aseg * 4;
            uint2 v = make_uint2(0u, 0u);
            if (k < NFEAT) {
                if (isbf) {
                    v = *(const uint2*)((const unsigned short*)feat_raw +
                                        (size_t)(r0 + arow) * NFEAT + k);
                } else {
                    const float4 f = *(const float4*)((const float*)feat_raw +
                                                      (size_t)(r0 + arow) * NFEAT + k);
                    v.x = ((unsigned int)f2bf(f.y) << 16) | f2bf(f.x);
                    v.y = ((unsigned int)f2bf(f.w) << 16) | f2bf(f.z);
                }
            }
            *(uint2*)&sA[arow * 56 + aseg * 4] = v;
        }
#pragma unroll
        for (int it = 0; it < 4; ++it) {
            const int idx = tid + 256 * it;
            const int row = idx >> 3, seg = idx & 7;
            const uint2 v = *(const uint2*)(wpad + (size_t)row * 512 + k0 + seg * 4);
            *(uint2*)&sB[row * 56 + seg * 4] = v;
        }
        __syncthreads();
        const short8 af = *(const short8*)&sA[(rt * 16 + m) * 56 + q * 8];
#pragma unroll
        for (int t = 0; t < 4; ++t) {
            const short8 bf = *(const short8*)&sB[((ch * 4 + t) * 16 + m) * 56 + q * 8];
            acc[t] = __builtin_amdgcn_mfma_f32_16x16x32_bf16(af, bf, acc[t], 0, 0, 0);
        }
    }

#pragma unroll
    for (int t = 0; t < 4; ++t) {
        const int col = (ch * 4 + t) * 16 + m;
        const float bb = bias[col];
#pragma unroll
        for (int r = 0; r < 4; ++r) {
            const int grow = r0 + rt * 16 + q * 4 + r;
            const float y = fmaxf(acc[t][r] + bb, 0.f);
            if (isbf) ((unsigned short*)out_raw)[(size_t)grow * OUTC + col] = f2bf(y);
            else      ((float*)out_raw)[(size_t)grow * OUTC + col] = y;
            const float ss = sum16(y * y);
            const float invn = 1.0f / fmaxf(sqrtf(ss), 1e-12f);
            xn[(size_t)grow * 128 + col] = y * invn;
        }
    }
}

// ---------------- linear via MFMA, bf16x3 split precision (~fp32 accuracy).
template<int FIN, int FOUT>
__global__ __launch_bounds__(256) void linear_mfma(
    const float* __restrict__ xin,
    const float* __restrict__ w,
    const float* __restrict__ bias,
    float* __restrict__ xn)
{
    constexpr int KP   = ((FIN + 31) / 32) * 32;
    constexpr int NCH  = KP / 32;
    constexpr int NTIL = 2 * (FOUT / 16);
    constexpr int MT   = (NTIL + 3) / 4;
    __shared__ short sAh[32 * 56], sAl[32 * 56];
    __shared__ short sBh[FOUT * 56], sBl[FOUT * 56];
    const int tid = threadIdx.x;
    const int l = tid & 63, wv = tid >> 6;
    const int m = l & 15, q = l >> 4;
    const int n0 = blockIdx.x * 32;

    floatx4 acc[MT];
#pragma unroll
    for (int i = 0; i < MT; ++i) acc[i] = 0;

    for (int c = 0; c < NCH; ++c) {
        const int k0 = c * 32;
        __syncthreads();
        {
            const int row = tid >> 3, seg = tid & 7;
            const int k = k0 + seg * 4;
            uint2 vh = make_uint2(0u, 0u), vl = make_uint2(0u, 0u);
            if (k < FIN) {
                const float4 f = *(const float4*)(xin + (size_t)(n0 + row) * FIN + k);
                const unsigned short h0 = f2bf(f.x), h1 = f2bf(f.y);
                const unsigned short h2 = f2bf(f.z), h3 = f2bf(f.w);
                const unsigned short e0 = f2bf(f.x - bf2f(h0)), e1 = f2bf(f.y - bf2f(h1));
                const unsigned short e2 = f2bf(f.z - bf2f(h2)), e3 = f2bf(f.w - bf2f(h3));
                vh = make_uint2(((unsigned)h1 << 16) | h0, ((unsigned)h3 << 16) | h2);
                vl = make_uint2(((unsigned)e1 << 16) | e0, ((unsigned)e3 << 16) | e2);
            }
            *(uint2*)&sAh[row * 56 + seg * 4] = vh;
            *(uint2*)&sAl[row * 56 + seg * 4] = vl;
        }
        for (int idx = tid; idx < FOUT * 8; idx += 256) {
            const int row = idx >> 3, seg = idx & 7;
            const int k = k0 + seg * 4;
            uint2 vh = make_uint2(0u, 0u), vl = make_uint2(0u, 0u);
            if (k < FIN) {
                const float4 f = *(const float4*)(w + (size_t)row * FIN + k);
                const unsigned short h0 = f2bf(f.x), h1 = f2bf(f.y);
                const unsigned short h2 = f2bf(f.z), h3 = f2bf(f.w);
                const unsigned short e0 = f2bf(f.x - bf2f(h0)), e1 = f2bf(f.y - bf2f(h1));
                const unsigned short e2 = f2bf(f.z - bf2f(h2)), e3 = f2bf(f.w - bf2f(h3));
                vh = make_uint2(((unsigned)h1 << 16) | h0, ((unsigned)h3 << 16) | h2);
                vl = make_uint2(((unsigned)e1 << 16) | e0, ((unsigned)e3 << 16) | e2);
            }
            *(uint2*)&sBh[row * 56 + seg * 4] = vh;
            *(uint2*)&sBl[row * 56 + seg * 4] = vl;
        }
        __syncthreads();
#pragma unroll
        for (int ti = 0; ti < MT; ++ti) {
            const int t = wv + ti * 4;
            if (t < NTIL) {
                const int rt = t & 1, ct = t >> 1;
                const int ao = (rt * 16 + m) * 56 + q * 8;
                const int bo = (ct * 16 + m) * 56 + q * 8;
                const short8 ah = *(const short8*)&sAh[ao];
                const short8 al = *(const short8*)&sAl[ao];
                const short8 bh = *(const short8*)&sBh[bo];
                const short8 bl = *(const short8*)&sBl[bo];
                floatx4 a = acc[ti];
                a = __builtin_amdgcn_mfma_f32_16x16x32_bf16(ah, bh, a, 0, 0, 0);
                a = __builtin_amdgcn_mfma_f32_16x16x32_bf16(ah, bl, a, 0, 0, 0);
                a = __builtin_amdgcn_mfma_f32_16x16x32_bf16(al, bh, a, 0, 0, 0);
                acc[ti] = a;
            }
        }
    }
#pragma unroll
    for (int ti = 0; ti < MT; ++ti) {
        const int t = wv + ti * 4;
        if (t < NTIL) {
            const int rt = t & 1, ct = t >> 1;
            const int col = ct * 16 + m;
            const float bb = bias[col];
#pragma unroll
            for (int r = 0; r < 4; ++r) {
                const int grow = n0 + rt * 16 + q * 4 + r;
                const float y = acc[ti][r] + bb;
                const float ss = sum16(y * y);
                const float invn = __builtin_amdgcn_rsqf(fmaxf(ss, 1e-24f));
                xn[(size_t)grow * FOUT + col] = y * invn;
            }
        }
    }
}

// ---------------- routing v10: v9 with z0 moved LDS->registers (PINned).
// lane = m(3b) | k(2-3b) | [nsub]; lane owns capsule k of neighbors m, m+8.
//  - z0 (neighbor m): 16 floats, PINned registers, persistent across iters
//  - z1 (neighbor m+8): private LDS [4][256] float4 = 16 KB (halved from 32)
//    -> LDS allows 10 blocks/CU; workgroup cap 8 -> up to 32 waves/CU
//  - dot in-register; softmax over k: DPP rot8 + shfl16 [+32]; no barriers
//  - neighbor sum: 3-stage DPP butterfly over 8 m-lanes
//  - x re-read from L2 after butterfly (loop-invariant address)
template<int K, int NPW>
__global__ __launch_bounds__(256) void routing_v10(
    const float* __restrict__ xn,
    const int* __restrict__ nb,
    float* __restrict__ xout,
    void* __restrict__ out_raw,
    const int* __restrict__ flag,
    const int coloff)
{
    constexpr int KD16 = K * 16;
    __shared__ float4 zl[4][256];          // z1 only: 16 KB
    const int tid = threadIdx.x;
    const int l = tid & 63, wv = tid >> 6;
    const int m = l & 7;
    const int k = (l >> 3) & (NPW == 2 ? 3 : 7);
    const int nsub = (NPW == 2) ? (l >> 5) : 0;
    const int node = blockIdx.x * (4 * NPW) + wv * NPW + nsub;
    const bool kv = (k < K);
    const bool isbf = (*flag != 0);
    const int nid0 = nb[(size_t)node * 16 + m];
    const int nid1 = nb[(size_t)node * 16 + m + 8];

    v2f z0[8], u[8];
    {
        const float* z0p = xn + (size_t)nid0 * KD16 + k * 16;
        const float* z1p = xn + (size_t)nid1 * KD16 + k * 16;
        const float* xp  = xn + (size_t)node * KD16 + k * 16;
#pragma unroll
        for (int q = 0; q < 4; ++q) {
            float4 a = make_float4(0.f, 0.f, 0.f, 0.f);
            float4 b = a, c = a;
            if (kv) {
                a = *(const float4*)(z0p + q * 4);
                b = *(const float4*)(z1p + q * 4);
                c = *(const float4*)(xp  + q * 4);
            }
            z0[2 * q] = (v2f){a.x, a.y}; z0[2 * q + 1] = (v2f){a.z, a.w};
            zl[q][tid] = b;
            u[2 * q] = (v2f){c.x, c.y}; u[2 * q + 1] = (v2f){c.z, c.w};
        }
    }
#pragma unroll
    for (int h = 0; h < 8; ++h) { PIN(z0[h]); }
    float invn = 1.0f;

    for (int t = 0; t < 5; ++t) {
        // agreement scores: z0 dot from registers, z1 dot streamed from LDS
        v2f d0 = pk_mul(z0[0], u[0]);
#pragma unroll
        for (int h = 1; h < 8; ++h) d0 = pk_fma(z0[h], u[h], d0);
        v2f d1;
        {
            const float4 A = zl[0][tid];
            d1 = pk_mul((v2f){A.x, A.y}, u[0]);
            d1 = pk_fma((v2f){A.z, A.w}, u[1], d1);
        }
#pragma unroll
        for (int q = 1; q < 4; ++q) {
            const float4 A = zl[q][tid];
            d1 = pk_fma((v2f){A.x, A.y}, u[2 * q],     d1);
            d1 = pk_fma((v2f){A.z, A.w}, u[2 * q + 1], d1);
        }
        const float p0 = kv ? (d0[0] + d0[1]) * invn : -1e4f;
        const float p1 = kv ? (d1[0] + d1[1]) * invn : -1e4f;
        float e0 = __expf(p0), e1 = __expf(p1);
        // softmax denominator over k-lanes: xor8 (DPP rot8) + xor16 [+ xor32]
        float s0 = dpp_add<0x128>(e0);
        float s1 = dpp_add<0x128>(e1);
        s0 += __shfl_xor(s0, 16);
        s1 += __shfl_xor(s1, 16);
        if (NPW == 1) {
            s0 += __shfl_xor(s0, 32);
            s1 += __shfl_xor(s1, 32);
        }
        e0 *= __builtin_amdgcn_rcpf(s0);
        e1 *= __builtin_amdgcn_rcpf(s1);
        const v2f ev0 = {e0, e0}, ev1 = {e1, e1};
        // aggregate: e0*z0 (regs) + e1*z1 (LDS streamed)
#pragma unroll
        for (int q = 0; q < 4; ++q) {
            const float4 A = zl[q][tid];
            u[2 * q]     = pk_fma(ev1, (v2f){A.x, A.y}, pk_mul(ev0, z0[2 * q]));
            u[2 * q + 1] = pk_fma(ev1, (v2f){A.z, A.w}, pk_mul(ev0, z0[2 * q + 1]));
        }
        // sum over 8 m-lanes: xor1, xor2, ^7 (stage-major DPP)
#pragma unroll
        for (int h = 0; h < 8; ++h) { u[h][0] = dpp_add<0xB1>(u[h][0]);  u[h][1] = dpp_add<0xB1>(u[h][1]); }
#pragma unroll
        for (int h = 0; h < 8; ++h) { u[h][0] = dpp_add<0x4E>(u[h][0]);  u[h][1] = dpp_add<0x4E>(u[h][1]); }
#pragma unroll
        for (int h = 0; h < 8; ++h) { u[h][0] = dpp_add<0x141>(u[h][0]); u[h][1] = dpp_add<0x141>(u[h][1]); }
        // + self term x (re-read from L2; loop-invariant address)
        {
            const float* xp = xn + (size_t)node * KD16 + k * 16;
#pragma unroll
            for (int q = 0; q < 4; ++q) {
                float4 c = make_float4(0.f, 0.f, 0.f, 0.f);
                if (kv) c = *(const float4*)(xp + q * 4);
                u[2 * q]     = pk_add(u[2 * q],     (v2f){c.x, c.y});
                u[2 * q + 1] = pk_add(u[2 * q + 1], (v2f){c.z, c.w});
            }
        }
        // capsule norm (fully in-register)
        if (t < 4) {
            v2f n0 = pk_mul(u[0], u[0]);
            v2f n1 = pk_mul(u[1], u[1]);
#pragma unroll
            for (int h = 2; h < 8; h += 2) {
                n0 = pk_fma(u[h],     u[h],     n0);
                n1 = pk_fma(u[h + 1], u[h + 1], n1);
            }
            invn = __builtin_amdgcn_rsqf(fmaxf(n0[0] + n0[1] + n1[0] + n1[1], 1e-24f));
        }
    }

    // relu + store (u replicated across the 8 m-lanes; m<4 write 4 dims each)
#pragma unroll
    for (int h = 0; h < 8; ++h) {
        u[h][0] = fmaxf(u[h][0], 0.f);
        u[h][1] = fmaxf(u[h][1], 0.f);
    }
    if (kv && m < 4) {
        v2f a = u[0], b = u[1];
        if (m == 1)      { a = u[2]; b = u[3]; }
        else if (m == 2) { a = u[4]; b = u[5]; }
        else if (m == 3) { a = u[6]; b = u[7]; }
        const float4 w4 = make_float4(a[0], a[1], b[0], b[1]);
        *(float4*)(xout + (size_t)node * KD16 + k * 16 + m * 4) = w4;
        const size_t ooff = (size_t)node * OUTC + coloff + k * 16 + m * 4;
        if (isbf) {
            uint2 pk;
            pk.x = ((unsigned int)f2bf(w4.y) << 16) | f2bf(w4.x);
            pk.y = ((unsigned int)f2bf(w4.w) << 16) | f2bf(w4.z);
            *(uint2*)((unsigned short*)out_raw + ooff) = pk;
        } else {
            *(float4*)((float*)out_raw + ooff) = w4;
        }
    }
}

extern "C" void kernel_launch(void* const* d_in, const int* in_sizes, int n_in,
                              void* d_out, int out_size, void* d_ws, size_t ws_size,
                              hipStream_t stream) {
    const int* nbid = (const int*)d_in[1];

    int*            flag  = (int*)d_ws;
    float*          wblob = (float*)((char*)d_ws + 16);
    unsigned short* wpad  = (unsigned short*)((char*)d_ws + (448 << 10));
    float*          xn    = (float*)((char*)d_ws + (1 << 20));
    float*          xc    = xn + (size_t)NNODES * 128;

    float* pw = wblob +      0; float* pb = wblob +  64000;
    float* w1 = wblob +  64128; float* b1 = wblob +  78464;
    float* w2 = wblob +  78576; float* b2 = wblob +  89328;
    float* w3 = wblob +  89424; float* b3 = wblob +  97104;
    float* w4 = wblob +  97184; float* b4 = wblob + 102304;
    float* w5 = wblob + 102368; float* b5 = wblob + 105440;

    hipLaunchKernelGGL(detect_kernel, dim3(1), dim3(64), 0, stream,
                       (const unsigned short*)d_in[0], flag);

    WPtrs wp;
    for (int i = 0; i < 12; ++i) wp.p[i] = d_in[i + 2];
    hipLaunchKernelGGL(convert_weights, dim3(413), dim3(256), 0, stream, wp, flag, wblob);
    hipLaunchKernelGGL(convert_wpad, dim3(256), dim3(256), 0, stream, pw, wpad);

    hipLaunchKernelGGL(pca_mfma, dim3(NNODES / 32), dim3(256), 0, stream,
                       d_in[0], wpad, pb, flag, xn, d_out);

    const int g1 = NNODES / 4;   // NPW=1: 4 nodes/block
    const int g2 = NNODES / 8;   // NPW=2: 8 nodes/block
    const int lgrid = NNODES / 32;

    hipLaunchKernelGGL((routing_v10<8, 1>), dim3(g1), dim3(256), 0, stream,
                       xn, nbid, xc, d_out, flag, 128);
    hipLaunchKernelGGL((linear_mfma<128, 112>), dim3(lgrid), dim3(256), 0, stream,
                       xc, w1, b1, xn);

    hipLaunchKernelGGL((routing_v10<7, 1>), dim3(g1), dim3(256), 0, stream,
                       xn, nbid, xc, d_out, flag, 256);
    hipLaunchKernelGGL((linear_mfma<112, 96>), dim3(lgrid), dim3(256), 0, stream,
                       xc, w2, b2, xn);

    hipLaunchKernelGGL((routing_v10<6, 1>), dim3(g1), dim3(256), 0, stream,
                       xn, nbid, xc, d_out, flag, 368);
    hipLaunchKernelGGL((linear_mfma<96, 80>), dim3(lgrid), dim3(256), 0, stream,
                       xc, w3, b3, xn);

    hipLaunchKernelGGL((routing_v10<5, 1>), dim3(g1), dim3(256), 0, stream,
                       xn, nbid, xc, d_out, flag, 464);
    hipLaunchKernelGGL((linear_mfma<80, 64>), dim3(lgrid), dim3(256), 0, stream,
                       xc, w4, b4, xn);

    hipLaunchKernelGGL((routing_v10<4, 2>), dim3(g2), dim3(256), 0, stream,
                       xn, nbid, xc, d_out, flag, 544);
    hipLaunchKernelGGL((linear_mfma<64, 48>), dim3(lgrid), dim3(256), 0, stream,
                       xc, w5, b5, xn);

    hipLaunchKernelGGL((routing_v10<3, 2>), dim3(g2), dim3(256), 0, stream,
                       xn, nbid, xc, d_out, flag, 608);
}

// Round 8
// 373.657 us; speedup vs baseline: 1.4613x; 1.1477x over previous
//
#include <hip/hip_runtime.h>
#include <hip/hip_bf16.h>
#include <cstdint>
#include <cstddef>

#define NNODES 20000
#define MNB    16
#define NFEAT  500
#define OUTC   656

typedef short short8 __attribute__((ext_vector_type(8)));
typedef float floatx4 __attribute__((ext_vector_type(4)));
typedef float v2f __attribute__((ext_vector_type(2)));

__device__ __forceinline__ float bf2f(unsigned int h) {
    union { unsigned int u; float f; } v; v.u = h << 16; return v.f;
}
__device__ __forceinline__ unsigned short f2bf(float f) {
    union { float f; unsigned int u; } v; v.f = f;
    unsigned int u = v.u;
    u += 0x7FFFu + ((u >> 16) & 1u);   // RNE
    return (unsigned short)(u >> 16);
}

// packed fp32 math (2x rate on CDNA): explicit VOP3P via asm.
__device__ __forceinline__ v2f pk_mul(v2f a, v2f b) {
    v2f d;
    asm("v_pk_mul_f32 %0, %1, %2 op_sel:[0,0] op_sel_hi:[1,1]"
        : "=v"(d) : "v"(a), "v"(b));
    return d;
}
__device__ __forceinline__ v2f pk_fma(v2f a, v2f b, v2f c) {
    v2f d;
    asm("v_pk_fma_f32 %0, %1, %2, %3 op_sel:[0,0,0] op_sel_hi:[1,1,1]"
        : "=v"(d) : "v"(a), "v"(b), "v"(c));
    return d;
}
__device__ __forceinline__ v2f pk_add(v2f a, v2f b) {
    v2f d;
    asm("v_pk_add_f32 %0, %1, %2 op_sel:[0,0] op_sel_hi:[1,1]"
        : "=v"(d) : "v"(a), "v"(b));
    return d;
}

// Opaque register pin: output of asm cannot be rematerialized from memory.
#define PIN(x) asm volatile("" : "+v"(x))

// DPP helpers. 0xB1 quad xor1, 0x4E quad xor2, 0x141 half-mirror (^7),
// 0x140 mirror (^15), 0x128 row_ror:8 (rot8 on 16 == xor8).
template<int CTRL>
__device__ __forceinline__ float dpp_add(float v) {
    const int o = __builtin_amdgcn_update_dpp(0, __float_as_int(v), CTRL, 0xF, 0xF, true);
    return v + __int_as_float(o);
}
__device__ __forceinline__ float sum16(float v) {
    v = dpp_add<0xB1>(v);
    v = dpp_add<0x4E>(v);
    v = dpp_add<0x141>(v);
    v = dpp_add<0x140>(v);
    return v;
}

// ---------------- dtype probe
__global__ __launch_bounds__(64) void detect_kernel(const unsigned short* __restrict__ fx,
                                                    int* __restrict__ flag) {
    const int tid = threadIdx.x;
    const unsigned short s = fx[2 * tid];
    const int e = (s >> 7) & 0xFF;
    const bool ok = (e >= 100 && e <= 140);
    const unsigned long long m = __ballot(ok);
    if (tid == 0) *flag = (__popcll(m) >= 32) ? 1 : 0;
}

// ---------------- convert all weights/biases to one fp32 blob in ws
struct WPtrs { const void* p[12]; };

__global__ __launch_bounds__(256) void convert_weights(WPtrs ptrs, const int* __restrict__ flag,
                                                       float* __restrict__ outb) {
    constexpr int SN[12] = {64000,128,14336,112,10752,96,7680,80,5120,64,3072,48};
    constexpr int SO[12] = {0,64000,64128,78464,78576,89328,89424,97104,97184,102304,102368,105440};
    constexpr int TOT = 105488;
    const int i = blockIdx.x * 256 + threadIdx.x;
    if (i >= TOT) return;
    const bool isbf = (*flag != 0);
    int seg = 0, local = i;
#pragma unroll
    for (int s = 0; s < 12; ++s) {
        if (i >= SO[s] && i < SO[s] + SN[s]) { seg = s; local = i - SO[s]; }
    }
    const void* src = ptrs.p[seg];
    float v;
    if (isbf) v = bf2f(((const unsigned short*)src)[local]);
    else      v = ((const float*)src)[local];
    outb[i] = v;
}

// ---------------- pad pca_w (fp32 blob) -> bf16 [128][512] (K-padded with zeros)
__global__ __launch_bounds__(256) void convert_wpad(const float* __restrict__ wblob,
                                                    unsigned short* __restrict__ wpad) {
    const int i = blockIdx.x * 256 + threadIdx.x;   // 128*512 = 65536
    const int n = i >> 9, k = i & 511;
    const float v = (k < NFEAT) ? wblob[n * NFEAT + k] : 0.f;
    wpad[i] = f2bf(v);
}

// ---------------- PCA via MFMA (fp32 OR bf16 feature; inline bf16 conversion)
__global__ __launch_bounds__(256) void pca_mfma(
    const void* __restrict__ feat_raw,
    const unsigned short* __restrict__ wpad,   // [128][512] bf16
    const float* __restrict__ bias,
    const int* __restrict__ flag,
    float* __restrict__ xn,
    void* __restrict__ out_raw)
{
    __shared__ short sA[32 * 56];   // stride 56 shorts (112 B): 2-way banks = free
    __shared__ short sB[128 * 56];
    const int tid = threadIdx.x;
    const int l = tid & 63, wv = tid >> 6;
    const int m = l & 15, q = l >> 4;
    const int rt = wv >> 1, ch = wv & 1;       // row-tile, col-half
    const int r0 = blockIdx.x * 32;
    const bool isbf = (*flag != 0);

    const int arow = tid >> 3, aseg = tid & 7;

    floatx4 acc[4];
#pragma unroll
    for (int t = 0; t < 4; ++t) acc[t] = 0;

    for (int c = 0; c < 16; ++c) {
        const int k0 = c * 32;
        __syncthreads();
        {
            const int k = k0 + aseg * 4;
            uint2 v = make_uint2(0u, 0u);
            if (k < NFEAT) {
                if (isbf) {
                    v = *(const uint2*)((const unsigned short*)feat_raw +
                                        (size_t)(r0 + arow) * NFEAT + k);
                } else {
                    const float4 f = *(const float4*)((const float*)feat_raw +
                                                      (size_t)(r0 + arow) * NFEAT + k);
                    v.x = ((unsigned int)f2bf(f.y) << 16) | f2bf(f.x);
                    v.y = ((unsigned int)f2bf(f.w) << 16) | f2bf(f.z);
                }
            }
            *(uint2*)&sA[arow * 56 + aseg * 4] = v;
        }
#pragma unroll
        for (int it = 0; it < 4; ++it) {
            const int idx = tid + 256 * it;
            const int row = idx >> 3, seg = idx & 7;
            const uint2 v = *(const uint2*)(wpad + (size_t)row * 512 + k0 + seg * 4);
            *(uint2*)&sB[row * 56 + seg * 4] = v;
        }
        __syncthreads();
        const short8 af = *(const short8*)&sA[(rt * 16 + m) * 56 + q * 8];
#pragma unroll
        for (int t = 0; t < 4; ++t) {
            const short8 bf = *(const short8*)&sB[((ch * 4 + t) * 16 + m) * 56 + q * 8];
            acc[t] = __builtin_amdgcn_mfma_f32_16x16x32_bf16(af, bf, acc[t], 0, 0, 0);
        }
    }

#pragma unroll
    for (int t = 0; t < 4; ++t) {
        const int col = (ch * 4 + t) * 16 + m;
        const float bb = bias[col];
#pragma unroll
        for (int r = 0; r < 4; ++r) {
            const int grow = r0 + rt * 16 + q * 4 + r;
            const float y = fmaxf(acc[t][r] + bb, 0.f);
            if (isbf) ((unsigned short*)out_raw)[(size_t)grow * OUTC + col] = f2bf(y);
            else      ((float*)out_raw)[(size_t)grow * OUTC + col] = y;
            const float ss = sum16(y * y);
            const float invn = 1.0f / fmaxf(sqrtf(ss), 1e-12f);
            xn[(size_t)grow * 128 + col] = y * invn;
        }
    }
}

// ---------------- linear via MFMA, bf16x3 split precision (~fp32 accuracy).
template<int FIN, int FOUT>
__global__ __launch_bounds__(256) void linear_mfma(
    const float* __restrict__ xin,
    const float* __restrict__ w,
    const float* __restrict__ bias,
    float* __restrict__ xn)
{
    constexpr int KP   = ((FIN + 31) / 32) * 32;
    constexpr int NCH  = KP / 32;
    constexpr int NTIL = 2 * (FOUT / 16);
    constexpr int MT   = (NTIL + 3) / 4;
    __shared__ short sAh[32 * 56], sAl[32 * 56];
    __shared__ short sBh[FOUT * 56], sBl[FOUT * 56];
    const int tid = threadIdx.x;
    const int l = tid & 63, wv = tid >> 6;
    const int m = l & 15, q = l >> 4;
    const int n0 = blockIdx.x * 32;

    floatx4 acc[MT];
#pragma unroll
    for (int i = 0; i < MT; ++i) acc[i] = 0;

    for (int c = 0; c < NCH; ++c) {
        const int k0 = c * 32;
        __syncthreads();
        {
            const int row = tid >> 3, seg = tid & 7;
            const int k = k0 + seg * 4;
            uint2 vh = make_uint2(0u, 0u), vl = make_uint2(0u, 0u);
            if (k < FIN) {
                const float4 f = *(const float4*)(xin + (size_t)(n0 + row) * FIN + k);
                const unsigned short h0 = f2bf(f.x), h1 = f2bf(f.y);
                const unsigned short h2 = f2bf(f.z), h3 = f2bf(f.w);
                const unsigned short e0 = f2bf(f.x - bf2f(h0)), e1 = f2bf(f.y - bf2f(h1));
                const unsigned short e2 = f2bf(f.z - bf2f(h2)), e3 = f2bf(f.w - bf2f(h3));
                vh = make_uint2(((unsigned)h1 << 16) | h0, ((unsigned)h3 << 16) | h2);
                vl = make_uint2(((unsigned)e1 << 16) | e0, ((unsigned)e3 << 16) | e2);
            }
            *(uint2*)&sAh[row * 56 + seg * 4] = vh;
            *(uint2*)&sAl[row * 56 + seg * 4] = vl;
        }
        for (int idx = tid; idx < FOUT * 8; idx += 256) {
            const int row = idx >> 3, seg = idx & 7;
            const int k = k0 + seg * 4;
            uint2 vh = make_uint2(0u, 0u), vl = make_uint2(0u, 0u);
            if (k < FIN) {
                const float4 f = *(const float4*)(w + (size_t)row * FIN + k);
                const unsigned short h0 = f2bf(f.x), h1 = f2bf(f.y);
                const unsigned short h2 = f2bf(f.z), h3 = f2bf(f.w);
                const unsigned short e0 = f2bf(f.x - bf2f(h0)), e1 = f2bf(f.y - bf2f(h1));
                const unsigned short e2 = f2bf(f.z - bf2f(h2)), e3 = f2bf(f.w - bf2f(h3));
                vh = make_uint2(((unsigned)h1 << 16) | h0, ((unsigned)h3 << 16) | h2);
                vl = make_uint2(((unsigned)e1 << 16) | e0, ((unsigned)e3 << 16) | e2);
            }
            *(uint2*)&sBh[row * 56 + seg * 4] = vh;
            *(uint2*)&sBl[row * 56 + seg * 4] = vl;
        }
        __syncthreads();
#pragma unroll
        for (int ti = 0; ti < MT; ++ti) {
            const int t = wv + ti * 4;
            if (t < NTIL) {
                const int rt = t & 1, ct = t >> 1;
                const int ao = (rt * 16 + m) * 56 + q * 8;
                const int bo = (ct * 16 + m) * 56 + q * 8;
                const short8 ah = *(const short8*)&sAh[ao];
                const short8 al = *(const short8*)&sAl[ao];
                const short8 bh = *(const short8*)&sBh[bo];
                const short8 bl = *(const short8*)&sBl[bo];
                floatx4 a = acc[ti];
                a = __builtin_amdgcn_mfma_f32_16x16x32_bf16(ah, bh, a, 0, 0, 0);
                a = __builtin_amdgcn_mfma_f32_16x16x32_bf16(ah, bl, a, 0, 0, 0);
                a = __builtin_amdgcn_mfma_f32_16x16x32_bf16(al, bh, a, 0, 0, 0);
                acc[ti] = a;
            }
        }
    }
#pragma unroll
    for (int ti = 0; ti < MT; ++ti) {
        const int t = wv + ti * 4;
        if (t < NTIL) {
            const int rt = t & 1, ct = t >> 1;
            const int col = ct * 16 + m;
            const float bb = bias[col];
#pragma unroll
            for (int r = 0; r < 4; ++r) {
                const int grow = n0 + rt * 16 + q * 4 + r;
                const float y = acc[ti][r] + bb;
                const float ss = sum16(y * y);
                const float invn = __builtin_amdgcn_rsqf(fmaxf(ss, 1e-24f));
                xn[(size_t)grow * FOUT + col] = y * invn;
            }
        }
    }
}

// ---------------- routing v11: FULLY register-resident. State = z0(16) +
// z1(16) + x(16) + u(16) = 64 floats/lane, all PINned; zero LDS, zero
// memory ops in the routing loop (pure pk-math + DPP). launch_bounds(256,1)
// removes the allocator's occupancy target so it will neither remat nor
// spill the pinned state (r7 proved PIN works when the state fits).
// lane = m(3b) | k(2-3b) | [nsub]; lane owns capsule k of neighbors m, m+8.
template<int K, int NPW>
__global__ __launch_bounds__(256, 1) void routing_v11(
    const float* __restrict__ xn,
    const int* __restrict__ nb,
    float* __restrict__ xout,
    void* __restrict__ out_raw,
    const int* __restrict__ flag,
    const int coloff)
{
    constexpr int KD16 = K * 16;
    const int tid = threadIdx.x;
    const int l = tid & 63, wv = tid >> 6;
    const int m = l & 7;
    const int k = (l >> 3) & (NPW == 2 ? 3 : 7);
    const int nsub = (NPW == 2) ? (l >> 5) : 0;
    const int node = blockIdx.x * (4 * NPW) + wv * NPW + nsub;
    const bool kv = (k < K);
    const bool isbf = (*flag != 0);
    const int nid0 = nb[(size_t)node * 16 + m];
    const int nid1 = nb[(size_t)node * 16 + m + 8];

    v2f z0[8], z1[8], x[8], u[8];
    {
        const float* z0p = xn + (size_t)nid0 * KD16 + k * 16;
        const float* z1p = xn + (size_t)nid1 * KD16 + k * 16;
        const float* xp  = xn + (size_t)node * KD16 + k * 16;
#pragma unroll
        for (int q = 0; q < 4; ++q) {
            float4 a = make_float4(0.f, 0.f, 0.f, 0.f);
            float4 b = a, c = a;
            if (kv) {
                a = *(const float4*)(z0p + q * 4);
                b = *(const float4*)(z1p + q * 4);
                c = *(const float4*)(xp  + q * 4);
            }
            z0[2 * q] = (v2f){a.x, a.y}; z0[2 * q + 1] = (v2f){a.z, a.w};
            z1[2 * q] = (v2f){b.x, b.y}; z1[2 * q + 1] = (v2f){b.z, b.w};
            x[2 * q]  = (v2f){c.x, c.y}; x[2 * q + 1]  = (v2f){c.z, c.w};
            u[2 * q]  = (v2f){c.x, c.y}; u[2 * q + 1]  = (v2f){c.z, c.w};
        }
    }
#pragma unroll
    for (int h = 0; h < 8; ++h) { PIN(z0[h]); PIN(z1[h]); PIN(x[h]); }
    float invn = 1.0f;

    for (int t = 0; t < 5; ++t) {
        // agreement scores (two interleaved packed chains, all registers)
        v2f d0 = pk_mul(z0[0], u[0]);
        v2f d1 = pk_mul(z1[0], u[0]);
#pragma unroll
        for (int h = 1; h < 8; ++h) {
            d0 = pk_fma(z0[h], u[h], d0);
            d1 = pk_fma(z1[h], u[h], d1);
        }
        const float p0 = kv ? (d0[0] + d0[1]) * invn : -1e4f;
        const float p1 = kv ? (d1[0] + d1[1]) * invn : -1e4f;
        float e0 = __expf(p0), e1 = __expf(p1);
        // softmax denominator over k-lanes: xor8 (DPP rot8) + xor16 [+ xor32]
        float s0 = dpp_add<0x128>(e0);
        float s1 = dpp_add<0x128>(e1);
        s0 += __shfl_xor(s0, 16);
        s1 += __shfl_xor(s1, 16);
        if (NPW == 1) {
            s0 += __shfl_xor(s0, 32);
            s1 += __shfl_xor(s1, 32);
        }
        e0 *= __builtin_amdgcn_rcpf(s0);
        e1 *= __builtin_amdgcn_rcpf(s1);
        const v2f ev0 = {e0, e0}, ev1 = {e1, e1};
        // aggregate this lane's two neighbors (registers only)
#pragma unroll
        for (int h = 0; h < 8; ++h)
            u[h] = pk_fma(ev1, z1[h], pk_mul(ev0, z0[h]));
        // sum over 8 m-lanes: xor1, xor2, ^7 (stage-major DPP)
#pragma unroll
        for (int h = 0; h < 8; ++h) { u[h][0] = dpp_add<0xB1>(u[h][0]);  u[h][1] = dpp_add<0xB1>(u[h][1]); }
#pragma unroll
        for (int h = 0; h < 8; ++h) { u[h][0] = dpp_add<0x4E>(u[h][0]);  u[h][1] = dpp_add<0x4E>(u[h][1]); }
#pragma unroll
        for (int h = 0; h < 8; ++h) { u[h][0] = dpp_add<0x141>(u[h][0]); u[h][1] = dpp_add<0x141>(u[h][1]); }
        // + self term x (registers)
#pragma unroll
        for (int h = 0; h < 8; ++h) u[h] = pk_add(u[h], x[h]);
        // capsule norm (fully in-register)
        if (t < 4) {
            v2f n0 = pk_mul(u[0], u[0]);
            v2f n1 = pk_mul(u[1], u[1]);
#pragma unroll
            for (int h = 2; h < 8; h += 2) {
                n0 = pk_fma(u[h],     u[h],     n0);
                n1 = pk_fma(u[h + 1], u[h + 1], n1);
            }
            invn = __builtin_amdgcn_rsqf(fmaxf(n0[0] + n0[1] + n1[0] + n1[1], 1e-24f));
        }
    }

    // relu + store (u replicated across the 8 m-lanes; m<4 write 4 dims each)
#pragma unroll
    for (int h = 0; h < 8; ++h) {
        u[h][0] = fmaxf(u[h][0], 0.f);
        u[h][1] = fmaxf(u[h][1], 0.f);
    }
    if (kv && m < 4) {
        v2f a = u[0], b = u[1];
        if (m == 1)      { a = u[2]; b = u[3]; }
        else if (m == 2) { a = u[4]; b = u[5]; }
        else if (m == 3) { a = u[6]; b = u[7]; }
        const float4 w4 = make_float4(a[0], a[1], b[0], b[1]);
        *(float4*)(xout + (size_t)node * KD16 + k * 16 + m * 4) = w4;
        const size_t ooff = (size_t)node * OUTC + coloff + k * 16 + m * 4;
        if (isbf) {
            uint2 pk;
            pk.x = ((unsigned int)f2bf(w4.y) << 16) | f2bf(w4.x);
            pk.y = ((unsigned int)f2bf(w4.w) << 16) | f2bf(w4.z);
            *(uint2*)((unsigned short*)out_raw + ooff) = pk;
        } else {
            *(float4*)((float*)out_raw + ooff) = w4;
        }
    }
}

extern "C" void kernel_launch(void* const* d_in, const int* in_sizes, int n_in,
                              void* d_out, int out_size, void* d_ws, size_t ws_size,
                              hipStream_t stream) {
    const int* nbid = (const int*)d_in[1];

    int*            flag  = (int*)d_ws;
    float*          wblob = (float*)((char*)d_ws + 16);
    unsigned short* wpad  = (unsigned short*)((char*)d_ws + (448 << 10));
    float*          xn    = (float*)((char*)d_ws + (1 << 20));
    float*          xc    = xn + (size_t)NNODES * 128;

    float* pw = wblob +      0; float* pb = wblob +  64000;
    float* w1 = wblob +  64128; float* b1 = wblob +  78464;
    float* w2 = wblob +  78576; float* b2 = wblob +  89328;
    float* w3 = wblob +  89424; float* b3 = wblob +  97104;
    float* w4 = wblob +  97184; float* b4 = wblob + 102304;
    float* w5 = wblob + 102368; float* b5 = wblob + 105440;

    hipLaunchKernelGGL(detect_kernel, dim3(1), dim3(64), 0, stream,
                       (const unsigned short*)d_in[0], flag);

    WPtrs wp;
    for (int i = 0; i < 12; ++i) wp.p[i] = d_in[i + 2];
    hipLaunchKernelGGL(convert_weights, dim3(413), dim3(256), 0, stream, wp, flag, wblob);
    hipLaunchKernelGGL(convert_wpad, dim3(256), dim3(256), 0, stream, pw, wpad);

    hipLaunchKernelGGL(pca_mfma, dim3(NNODES / 32), dim3(256), 0, stream,
                       d_in[0], wpad, pb, flag, xn, d_out);

    const int g1 = NNODES / 4;   // NPW=1: 4 nodes/block
    const int g2 = NNODES / 8;   // NPW=2: 8 nodes/block
    const int lgrid = NNODES / 32;

    hipLaunchKernelGGL((routing_v11<8, 1>), dim3(g1), dim3(256), 0, stream,
                       xn, nbid, xc, d_out, flag, 128);
    hipLaunchKernelGGL((linear_mfma<128, 112>), dim3(lgrid), dim3(256), 0, stream,
                       xc, w1, b1, xn);

    hipLaunchKernelGGL((routing_v11<7, 1>), dim3(g1), dim3(256), 0, stream,
                       xn, nbid, xc, d_out, flag, 256);
    hipLaunchKernelGGL((linear_mfma<112, 96>), dim3(lgrid), dim3(256), 0, stream,
                       xc, w2, b2, xn);

    hipLaunchKernelGGL((routing_v11<6, 1>), dim3(g1), dim3(256), 0, stream,
                       xn, nbid, xc, d_out, flag, 368);
    hipLaunchKernelGGL((linear_mfma<96, 80>), dim3(lgrid), dim3(256), 0, stream,
                       xc, w3, b3, xn);

    hipLaunchKernelGGL((routing_v11<5, 1>), dim3(g1), dim3(256), 0, stream,
                       xn, nbid, xc, d_out, flag, 464);
    hipLaunchKernelGGL((linear_mfma<80, 64>), dim3(lgrid), dim3(256), 0, stream,
                       xc, w4, b4, xn);

    hipLaunchKernelGGL((routing_v11<4, 2>), dim3(g2), dim3(256), 0, stream,
                       xn, nbid, xc, d_out, flag, 544);
    hipLaunchKernelGGL((linear_mfma<64, 48>), dim3(lgrid), dim3(256), 0, stream,
                       xc, w5, b5, xn);

    hipLaunchKernelGGL((routing_v11<3, 2>), dim3(g2), dim3(256), 0, stream,
                       xn, nbid, xc, d_out, flag, 608);
}